// Round 5
// baseline (317.243 us; speedup 1.0000x reference)
//
#include <hip/hip_runtime.h>
#include <hip/hip_bf16.h>

#define DEVI __device__ __forceinline__

typedef __attribute__((ext_vector_type(4))) float f32x4;
typedef __attribute__((ext_vector_type(16))) float f32x16;
typedef __attribute__((ext_vector_type(8))) short s16x8;
typedef __attribute__((ext_vector_type(4))) short s16x4;

DEVI ushort f2bf(float f) {
  union { float f; unsigned u; } v; v.f = f;
  unsigned r = v.u + 0x7FFFu + ((v.u >> 16) & 1u);
  return (ushort)(r >> 16);
}

DEVI void gload_lds16(const void* g, void* l) {
  __builtin_amdgcn_global_load_lds((const __attribute__((address_space(1))) void*)g,
                                   (__attribute__((address_space(3))) void*)l, 16, 0, 0);
}

#define MFMA16 __builtin_amdgcn_mfma_f32_16x16x32_bf16
#define SBAR() __builtin_amdgcn_s_barrier()
#define LGKM0() asm volatile("s_waitcnt lgkmcnt(0)")

// ---------------- elementwise cast ----------------
__global__ __launch_bounds__(256) void cast_bf16_k(const float* __restrict__ in,
                                                   ushort* __restrict__ out, int n) {
  int i = (blockIdx.x * 256 + threadIdx.x) * 4;
  if (i >= n) return;
  float4 v = *(const float4*)(in + i);
  ushort4 o;
  o.x = f2bf(v.x); o.y = f2bf(v.y); o.z = f2bf(v.z); o.w = f2bf(v.w);
  *(ushort4*)(out + i) = o;
}

// ---------------- transpose + cast: in (R,C) f32 -> out (C,R) bf16 ----------------
__global__ __launch_bounds__(256) void transpose_cast_k(const float* __restrict__ in,
                                                        ushort* __restrict__ out, int R, int C) {
  __shared__ ushort tile[64][66];
  const int r0 = blockIdx.y * 64, c0 = blockIdx.x * 64;
  const int tid = threadIdx.x;
  #pragma unroll
  for (int j = 0; j < 16; ++j) {
    int idx = j * 256 + tid;
    int r = idx >> 6, c = idx & 63;
    tile[c][r] = f2bf(in[(size_t)(r0 + r) * C + c0 + c]);
  }
  __syncthreads();
  #pragma unroll
  for (int j = 0; j < 16; ++j) {
    int idx = j * 256 + tid;
    int c = idx >> 6, r = idx & 63;
    out[(size_t)(c0 + c) * R + r0 + r] = tile[c][r];
  }
}

// ---------------- RoPE tables ----------------
__global__ __launch_bounds__(256) void rope_table_k(float2* __restrict__ tab) {
  int idx = blockIdx.x * 256 + threadIdx.x;   // T*32 = 65536
  int t = idx >> 5, i = idx & 31;
  float inv = expf(-(float)i * 0.28782313662425575f);  // ln(10000)/32
  float ang = (float)t * inv;
  tab[idx] = make_float2(cosf(ang), sinf(ang));
}

// =====================================================================
// 256x256 4-phase GEMM: C(M,N) = A(M,K) bf16 @ BT(N,K)^T bf16
// 8 waves (2M x 4N), wave tile 128x64, BK=64, double-buffered LDS (128 KiB),
// counted vmcnt(6), per-phase builtin barriers, setprio on MFMA, swizzled LDS,
// bijective XCD grid swizzle.
// amdgpu_waves_per_eu(2,2): pins allocator to 2 waves/EU (256-VGPR budget).
// Validated round 4 on the Wo GEMM: spill eliminated (160 -> ~84 us on a
// half-chip grid).  __launch_bounds__(512,{1,2}) had the allocator targeting
// 4 waves/EU (128-reg cap) and spilling ~80 regs/thread (rounds 1-3).
// EPI=0: plain f32 C store.  EPI=1: RoPE epilogue + Qp/Kp/Vp fragment pack
// (fragment mapping bit-verified in rounds 1-3: absmax identical to baseline).
// =====================================================================
template <int M, int N, int K, int EPI>
__global__ __attribute__((amdgpu_flat_work_group_size(512, 512)))
__attribute__((amdgpu_waves_per_eu(2, 2)))
void gemm256(const ushort* __restrict__ A,
             const ushort* __restrict__ BT,
             const float2* __restrict__ tab,
             float* __restrict__ C,
             ushort* __restrict__ Qp,
             ushort* __restrict__ Kp,
             ushort* __restrict__ Vp) {
  constexpr int NKT = K / 64;
  constexpr int GX = N / 256;
  constexpr int NWG = (M / 256) * GX;
  __shared__ __attribute__((aligned(128))) ushort smem[65536];   // 128 KiB

  const int tid = threadIdx.x;
  const int ln = tid & 63, wv = tid >> 6;
  const int g = ln >> 4, l15 = ln & 15, l31 = ln & 31, hi = ln >> 5;
  const int wm = wv >> 2, wn = wv & 3;
  const int wub = tid & ~63;            // wave-uniform lane-group base

  // bijective XCD swizzle (NWG % 8 == 0 for both instantiations)
  const int orig = blockIdx.x;
  const int wg = (orig & 7) * (NWG / 8) + (orig >> 3);
  const int bx = wg % GX, by = wg / GX;
  const int m0 = by * 256, n0 = bx * 256;

  ushort* Asm = smem;                   // [buf][half][128*64]
  ushort* Bsm = smem + 32768;

  auto stageA = [&](int t, int h) {
    const ushort* gs = A + (size_t)(m0 + h * 128) * K + t * 64;
    ushort* ld = Asm + (t & 1) * 16384 + h * 8192;
    #pragma unroll
    for (int j = 0; j < 2; ++j) {
      int ci = j * 512 + tid;
      int row = ci >> 3, c = ci & 7;
      gload_lds16(gs + (size_t)row * K + ((c ^ (row & 7)) << 3),
                  ld + (size_t)(j * 512 + wub) * 8);
    }
  };
  auto stageB = [&](int t, int h) {
    const ushort* gs = BT + (size_t)(n0 + h * 128) * K + t * 64;
    ushort* ld = Bsm + (t & 1) * 16384 + h * 8192;
    #pragma unroll
    for (int j = 0; j < 2; ++j) {
      int ci = j * 512 + tid;
      int row = ci >> 3, c = ci & 7;
      gload_lds16(gs + (size_t)row * K + ((c ^ (row & 7)) << 3),
                  ld + (size_t)(j * 512 + wub) * 8);
    }
  };
  auto ldfrag = [&](const ushort* half, int row, int kc) -> s16x8 {
    return *(const s16x8*)((const char*)half + row * 128 + ((kc ^ (row & 7)) << 4));
  };

  f32x4 acc[8][4];
  #pragma unroll
  for (int i = 0; i < 8; ++i)
    #pragma unroll
    for (int j = 0; j < 4; ++j) acc[i][j] = (f32x4){0.f, 0.f, 0.f, 0.f};

  // ---- prologue: tile0 full + tile1 {B0,B1,A0} ----
  stageB(0, 0); stageB(0, 1); stageA(0, 0); stageA(0, 1);
  stageB(1, 0); stageB(1, 1); stageA(1, 0);
  asm volatile("s_waitcnt vmcnt(6)" ::: "memory");
  SBAR();

  #pragma unroll 1
  for (int t = 0; t < NKT; ++t) {
    const ushort* Ah = Asm + (t & 1) * 16384 + wm * 8192;
    const ushort* Bh = Bsm + (t & 1) * 16384 + (wn >> 1) * 8192;
    s16x8 af[4][2], bfr[4][2];

    // ---- q0: read all B + A-low; stage (t+1).A1; MFMA a0*b01 ----
    #pragma unroll
    for (int ks = 0; ks < 2; ++ks) {
      #pragma unroll
      for (int ni = 0; ni < 4; ++ni)
        bfr[ni][ks] = ldfrag(Bh, (wn & 1) * 64 + ni * 16 + l15, ks * 4 + g);
      #pragma unroll
      for (int mi = 0; mi < 4; ++mi)
        af[mi][ks] = ldfrag(Ah, mi * 16 + l15, ks * 4 + g);
    }
    if (t + 1 < NKT) stageA(t + 1, 1);
    SBAR();
    LGKM0();
    __builtin_amdgcn_s_setprio(1);
    #pragma unroll
    for (int mi = 0; mi < 4; ++mi)
      #pragma unroll
      for (int ni = 0; ni < 2; ++ni)
        #pragma unroll
        for (int ks = 0; ks < 2; ++ks)
          acc[mi][ni] = MFMA16(af[mi][ks], bfr[ni][ks], acc[mi][ni], 0, 0, 0);
    __builtin_amdgcn_s_setprio(0);
    SBAR();

    // ---- q1: stage (t+2).B0; MFMA a0*b23 ----
    if (t + 2 < NKT) stageB(t + 2, 0);
    SBAR();
    __builtin_amdgcn_s_setprio(1);
    #pragma unroll
    for (int mi = 0; mi < 4; ++mi)
      #pragma unroll
      for (int ni = 0; ni < 2; ++ni)
        #pragma unroll
        for (int ks = 0; ks < 2; ++ks)
          acc[mi][2 + ni] = MFMA16(af[mi][ks], bfr[2 + ni][ks], acc[mi][2 + ni], 0, 0, 0);
    __builtin_amdgcn_s_setprio(0);
    SBAR();

    // ---- q2: read A-high (reuse af); stage (t+2).B1; MFMA a1*b01 ----
    #pragma unroll
    for (int ks = 0; ks < 2; ++ks)
      #pragma unroll
      for (int mi = 0; mi < 4; ++mi)
        af[mi][ks] = ldfrag(Ah, 64 + mi * 16 + l15, ks * 4 + g);
    if (t + 2 < NKT) stageB(t + 2, 1);
    SBAR();
    LGKM0();
    __builtin_amdgcn_s_setprio(1);
    #pragma unroll
    for (int mi = 0; mi < 4; ++mi)
      #pragma unroll
      for (int ni = 0; ni < 2; ++ni)
        #pragma unroll
        for (int ks = 0; ks < 2; ++ks)
          acc[4 + mi][ni] = MFMA16(af[mi][ks], bfr[ni][ks], acc[4 + mi][ni], 0, 0, 0);
    __builtin_amdgcn_s_setprio(0);
    SBAR();

    // ---- q3: stage (t+2).A0; MFMA a1*b23; counted vmcnt ----
    if (t + 2 < NKT) stageA(t + 2, 0);
    SBAR();
    __builtin_amdgcn_s_setprio(1);
    #pragma unroll
    for (int mi = 0; mi < 4; ++mi)
      #pragma unroll
      for (int ni = 0; ni < 2; ++ni)
        #pragma unroll
        for (int ks = 0; ks < 2; ++ks)
          acc[4 + mi][2 + ni] = MFMA16(af[mi][ks], bfr[2 + ni][ks], acc[4 + mi][2 + ni], 0, 0, 0);
    __builtin_amdgcn_s_setprio(0);
    if (t + 2 < NKT)      asm volatile("s_waitcnt vmcnt(6)" ::: "memory");
    else if (t + 1 < NKT) asm volatile("s_waitcnt vmcnt(0)" ::: "memory");
    SBAR();
  }

  if constexpr (EPI == 0) {
    // plain f32 store
    #pragma unroll
    for (int mi = 0; mi < 8; ++mi)
      #pragma unroll
      for (int r = 0; r < 4; ++r) {
        int row = m0 + wm * 128 + mi * 16 + g * 4 + r;
        float* crow = C + (size_t)row * N + n0 + wn * 64 + l15;
        #pragma unroll
        for (int ni = 0; ni < 4; ++ni) crow[ni * 16] = acc[mi][ni][r];
      }
  } else {
    // ---- RoPE epilogue + fragment pack (two 128-row passes through LDS) ----
    const int bq = by >> 3;              // batch
    const int tb0 = (by & 7) * 256;      // batch-local row base of this block
    const int type = (bx < 8) ? 0 : (bx < 10 ? 1 : 2);   // Q / K / V per block
    constexpr int OST = 260;             // Ot stride (elements)

    __syncthreads();                     // all waves out of the K-loop
    #pragma unroll 1
    for (int hm = 0; hm < 2; ++hm) {
      if (wm == hm) {
        #pragma unroll
        for (int mi = 0; mi < 8; ++mi)
          #pragma unroll
          for (int r = 0; r < 4; ++r) {
            const int tl = mi * 16 + g * 4 + r;
            const int t = tb0 + hm * 128 + tl;
            #pragma unroll
            for (int ni = 0; ni < 4; ++ni) {
              const int cl = wn * 64 + ni * 16 + l15;
              float val = acc[mi][ni][r], outv;
              if (type < 2) {
                float pairv = acc[mi][ni ^ 2][r];
                float2 cs = tab[t * 32 + (ni & 1) * 16 + l15];
                outv = (ni & 2) ? (val * cs.x + pairv * cs.y) : (val * cs.x - pairv * cs.y);
                if (type == 0) outv *= 0.18033688011112042f;   // 0.125 * log2(e)
              } else {
                outv = val;
              }
              smem[tl * OST + cl] = f2bf(outv);
            }
          }
      }
      __syncthreads();
      // 64 chunks for this 128-row half: id = wv*8+it
      #pragma unroll
      for (int it = 0; it < 8; ++it) {
        const int id = wv * 8 + it;
        const int hl = id >> 4, q4 = (id >> 2) & 3, fi = id & 3;
        const int tile = (by & 7) * 8 + hm * 4 + q4;
        if (type < 2) {
          const ushort* srow = smem + (q4 * 32 + l31) * OST + hl * 64 + fi * 16 + hi * 8;
          union { s16x4 h[2]; s16x8 v; } u;
          u.h[0] = *(const s16x4*)srow;
          u.h[1] = *(const s16x4*)(srow + 4);
          ushort* dst;
          if (type == 0) {
            const int h = bx * 4 + hl;
            dst = Qp + (((size_t)(bq * 32 + h) * 64 + tile) * 4 + fi) * 512 + ln * 8;
          } else {
            const int h = (bx - 8) * 4 + hl;
            dst = Kp + (((size_t)(bq * 8 + h) * 64 + tile) * 4 + fi) * 512 + ln * 8;
          }
          *(s16x8*)dst = u.v;
        } else {
          const int hk = (bx - 10) * 4 + hl;
          const int col = hl * 64 + (fi & 1) * 32 + l31;
          const int row0 = q4 * 32 + (fi >> 1) * 16 + hi * 8;
          union { ushort o[8]; s16x8 v; } u;
          #pragma unroll
          for (int j2 = 0; j2 < 8; ++j2) u.o[j2] = smem[(row0 + j2) * OST + col];
          ushort* dst = Vp + (((size_t)(bq * 8 + hk) * 64 + tile) * 4 + fi) * 512 + ln * 8;
          *(s16x8*)dst = u.v;
        }
      }
      __syncthreads();
    }
  }
}

// ---------------- causal GQA flash attention, swapped-QK^T 32x32, barrier-free ----------------
__global__ __launch_bounds__(256) void attn_k(const ushort* __restrict__ Qp,
                                              const ushort* __restrict__ Kp,
                                              const ushort* __restrict__ Vp,
                                              ushort* __restrict__ O) {
  __shared__ ushort ep[4][32 * 64];   // per-wave epilogue transpose patch
  const int tid = threadIdx.x, wv = tid >> 6, ln = tid & 63;
  const int l31 = ln & 31, hi = ln >> 5;

  const int f = blockIdx.x + gridDim.x * (blockIdx.y + 32 * blockIdx.z);  // 0..1023
  const int xcd = f & 7, j = f >> 3;         // j: 0..127
  const int pr = xcd + 8 * (j & 1);          // (b,hk) pair id, 0..15
  const int b = pr >> 3, hk = pr & 7;
  const int s = j >> 1;                      // 0..63
  const int hq = hk * 4 + (s & 3);
  const int qtile = 63 - ((s >> 2) * 4 + wv);   // LJF
  const int qw = qtile * 32;
  const int nt = qtile + 1;

  const ushort* Qh    = Qp + ((size_t)(b * 32 + hq)) * (64 * 2048);
  const ushort* Kbase = Kp + ((size_t)(b * 8 + hk)) * (64 * 2048);
  const ushort* Vbase = Vp + ((size_t)(b * 8 + hk)) * (64 * 2048);
  ushort* lds = ep[wv];

  s16x8 qf[4];
  {
    const ushort* qp_ = Qh + (size_t)qtile * 2048 + ln * 8;
    #pragma unroll
    for (int ks = 0; ks < 4; ++ks) qf[ks] = *(const s16x8*)(qp_ + ks * 512);
  }

  f32x16 oacc[2];
  #pragma unroll
  for (int dt = 0; dt < 2; ++dt)
    #pragma unroll
    for (int r = 0; r < 16; ++r) oacc[dt][r] = 0.f;
  float m = -1e30f, l = 0.f;

  const ushort* kp = Kbase + ln * 8;
  const ushort* vp = Vbase + ln * 8;

  s16x8 kf[4];
  #pragma unroll
  for (int ks = 0; ks < 4; ++ks) kf[ks] = *(const s16x8*)(kp + ks * 512);
  kp += 2048;

  s16x8 vc[4];
  union pfu { unsigned u[4]; s16x8 v; };
  pfu pf0, pf1;

  #pragma unroll 1
  for (int kt = 0; kt < nt; ++kt) {
    if (kt) {
      __builtin_amdgcn_s_setprio(1);
      oacc[0] = __builtin_amdgcn_mfma_f32_32x32x16_bf16(vc[0], pf0.v, oacc[0], 0, 0, 0);
      oacc[1] = __builtin_amdgcn_mfma_f32_32x32x16_bf16(vc[1], pf0.v, oacc[1], 0, 0, 0);
      oacc[0] = __builtin_amdgcn_mfma_f32_32x32x16_bf16(vc[2], pf1.v, oacc[0], 0, 0, 0);
      oacc[1] = __builtin_amdgcn_mfma_f32_32x32x16_bf16(vc[3], pf1.v, oacc[1], 0, 0, 0);
      __builtin_amdgcn_s_setprio(0);
    }
    #pragma unroll
    for (int fi2 = 0; fi2 < 4; ++fi2) vc[fi2] = *(const s16x8*)(vp + fi2 * 512);
    vp += 2048;

    f32x16 sp;
    #pragma unroll
    for (int r = 0; r < 16; ++r) sp[r] = 0.f;
    __builtin_amdgcn_s_setprio(1);
    #pragma unroll
    for (int ks = 0; ks < 4; ++ks)
      sp = __builtin_amdgcn_mfma_f32_32x32x16_bf16(kf[ks], qf[ks], sp, 0, 0, 0);
    __builtin_amdgcn_s_setprio(0);

    if (kt + 1 < nt) {
      #pragma unroll
      for (int ks = 0; ks < 4; ++ks) kf[ks] = *(const s16x8*)(kp + ks * 512);
      kp += 2048;
    }

    if (kt == qtile) {
      #pragma unroll
      for (int r = 0; r < 16; ++r) {
        int key = (r & 3) + 8 * (r >> 2) + 4 * hi;
        if (key > l31) sp[r] = -1e30f;
      }
    }

    float t0 = fmaxf(fmaxf(sp[0], sp[1]), sp[2]);
    float t1 = fmaxf(fmaxf(sp[3], sp[4]), sp[5]);
    float t2 = fmaxf(fmaxf(sp[6], sp[7]), sp[8]);
    float t3 = fmaxf(fmaxf(sp[9], sp[10]), sp[11]);
    float t4 = fmaxf(fmaxf(sp[12], sp[13]), sp[14]);
    float u0 = fmaxf(fmaxf(t0, t1), t2);
    float u1 = fmaxf(fmaxf(t3, t4), sp[15]);
    float pm = fmaxf(u0, u1);
    pm = fmaxf(pm, __shfl_xor(pm, 32, 64));

    if (__any(pm > m)) {
      float mn = fmaxf(m, pm);
      float alpha = __builtin_amdgcn_exp2f(m - mn);
      m = mn;
      l *= alpha;
      #pragma unroll
      for (int dt = 0; dt < 2; ++dt)
        #pragma unroll
        for (int r = 0; r < 16; ++r) oacc[dt][r] *= alpha;
    }

    #pragma unroll
    for (int r = 0; r < 16; ++r) sp[r] = __builtin_amdgcn_exp2f(sp[r] - m);
    {
      float a0 = sp[0] + sp[1], a1 = sp[2] + sp[3], a2 = sp[4] + sp[5], a3 = sp[6] + sp[7];
      float a4 = sp[8] + sp[9], a5 = sp[10] + sp[11], a6 = sp[12] + sp[13], a7 = sp[14] + sp[15];
      float b0 = a0 + a1, b1 = a2 + a3, b2 = a4 + a5, b3 = a6 + a7;
      float rs = (b0 + b1) + (b2 + b3);
      rs += __shfl_xor(rs, 32, 64);
      l += rs;
    }

    unsigned cw[8], xs[8];
    #pragma unroll
    for (int jj = 0; jj < 8; ++jj) {
      union { __hip_bfloat162 h; unsigned u; } pk;
      pk.h = __float22bfloat162_rn(make_float2(sp[2 * jj], sp[2 * jj + 1]));
      cw[jj] = pk.u;
    }
    #pragma unroll
    for (int jj = 0; jj < 8; ++jj) xs[jj] = __shfl_xor(cw[jj], 32, 64);
    pf0.u[0] = hi ? xs[2] : cw[0];
    pf0.u[1] = hi ? xs[3] : cw[1];
    pf0.u[2] = hi ? cw[2] : xs[0];
    pf0.u[3] = hi ? cw[3] : xs[1];
    pf1.u[0] = hi ? xs[6] : cw[4];
    pf1.u[1] = hi ? xs[7] : cw[5];
    pf1.u[2] = hi ? cw[6] : xs[4];
    pf1.u[3] = hi ? cw[7] : xs[5];
  }

  __builtin_amdgcn_s_setprio(1);
  oacc[0] = __builtin_amdgcn_mfma_f32_32x32x16_bf16(vc[0], pf0.v, oacc[0], 0, 0, 0);
  oacc[1] = __builtin_amdgcn_mfma_f32_32x32x16_bf16(vc[1], pf0.v, oacc[1], 0, 0, 0);
  oacc[0] = __builtin_amdgcn_mfma_f32_32x32x16_bf16(vc[2], pf1.v, oacc[0], 0, 0, 0);
  oacc[1] = __builtin_amdgcn_mfma_f32_32x32x16_bf16(vc[3], pf1.v, oacc[1], 0, 0, 0);
  __builtin_amdgcn_s_setprio(0);

  float invl = 1.0f / l;
  #pragma unroll
  for (int dt = 0; dt < 2; ++dt)
    #pragma unroll
    for (int r = 0; r < 16; ++r) {
      int d = dt * 32 + (r & 3) + 8 * (r >> 2) + 4 * hi;
      int byte = (l31 * 128 + d * 2) ^ ((l31 & 7) << 4);
      *(ushort*)((char*)lds + byte) = f2bf(oacc[dt][r] * invl);
    }
  const int qr = ln >> 1, half = ln & 1;
  #pragma unroll
  for (int jj = 0; jj < 4; ++jj) {
    int byte = (qr * 128 + half * 64 + jj * 16) ^ ((qr & 7) << 4);
    s16x8 vrow = *(const s16x8*)((const char*)lds + byte);
    *(s16x8*)(O + ((size_t)(b * 2048 + qw + qr)) * 2048 + hq * 64 + half * 32 + jj * 8) = vrow;
  }
}

extern "C" void kernel_launch(void* const* d_in, const int* in_sizes, int n_in,
                              void* d_out, int out_size, void* d_ws, size_t ws_size,
                              hipStream_t stream) {
  const float* x   = (const float*)d_in[0];
  const float* Wq  = (const float*)d_in[1];
  const float* Wkv = (const float*)d_in[2];
  const float* Wo  = (const float*)d_in[3];
  float* out = (float*)d_out;

  char* ws = (char*)d_ws;
  ushort* xb     = (ushort*)(ws);                 // 16 MiB  x bf16 (4096x2048)
  ushort* WqkvT  = (ushort*)(ws + 16777216);      // 12 MiB  [Wq|Wkv]^T bf16 (3072x2048)
  ushort* WoT    = (ushort*)(ws + 29360128);      //  8 MiB  Wo^T bf16 (2048x2048)
  float2* tab    = (float2*)(ws + 37748736);      // 512 KiB rope tables
  ushort* Qp     = (ushort*)(ws + 38273024);      // 16 MiB  Q packed
  ushort* Kp     = (ushort*)(ws + 55050240);      //  4 MiB  K packed
  ushort* Vp     = (ushort*)(ws + 59244544);      //  4 MiB  V packed
  ushort* Ob     = (ushort*)(ws + 63438848);      // 16 MiB  attn out bf16 (4096x2048)

  cast_bf16_k<<<8192, 256, 0, stream>>>(x, xb, 2 * 2048 * 2048);
  transpose_cast_k<<<dim3(32, 32), 256, 0, stream>>>(Wq, WqkvT, 2048, 2048);
  transpose_cast_k<<<dim3(16, 32), 256, 0, stream>>>(Wkv, WqkvT + 2048 * 2048, 2048, 1024);
  transpose_cast_k<<<dim3(32, 32), 256, 0, stream>>>(Wo, WoT, 2048, 2048);
  rope_table_k<<<256, 256, 0, stream>>>(tab);
  gemm256<4096, 3072, 2048, 1><<<192, 512, 0, stream>>>(xb, WqkvT, tab, (float*)nullptr, Qp, Kp, Vp);
  attn_k<<<dim3(16, 32, 2), 256, 0, stream>>>(Qp, Kp, Vp, Ob);
  gemm256<4096, 2048, 2048, 0><<<128, 512, 0, stream>>>(Ob, WoT, (const float2*)nullptr, out,
                                                        (ushort*)nullptr, (ushort*)nullptr, (ushort*)nullptr);
}

// Round 6
// 302.566 us; speedup vs baseline: 1.0485x; 1.0485x over previous
//
#include <hip/hip_runtime.h>
#include <hip/hip_bf16.h>

#define DEVI __device__ __forceinline__

typedef __attribute__((ext_vector_type(4))) float f32x4;
typedef __attribute__((ext_vector_type(16))) float f32x16;
typedef __attribute__((ext_vector_type(8))) short s16x8;
typedef __attribute__((ext_vector_type(4))) short s16x4;

DEVI ushort f2bf(float f) {
  union { float f; unsigned u; } v; v.f = f;
  unsigned r = v.u + 0x7FFFu + ((v.u >> 16) & 1u);
  return (ushort)(r >> 16);
}

DEVI void gload_lds16(const void* g, void* l) {
  __builtin_amdgcn_global_load_lds((const __attribute__((address_space(1))) void*)g,
                                   (__attribute__((address_space(3))) void*)l, 16, 0, 0);
}

#define MFMA16 __builtin_amdgcn_mfma_f32_16x16x32_bf16
#define SBAR() __builtin_amdgcn_s_barrier()
#define LGKM0() asm volatile("s_waitcnt lgkmcnt(0)")

// Stage NITER*256 16B chunks into LDS. Tile rows are 64 bf16 = 128B (8 chunks).
template <int NITER>
DEVI void stage_swz(const ushort* __restrict__ gsrc, int stride_elems, ushort* lds, int tid) {
  const int wv = tid >> 6, ln = tid & 63;
  #pragma unroll
  for (int j = 0; j < NITER; ++j) {
    const int ci = j * 256 + wv * 64 + ln;
    const int row = ci >> 3, c = ci & 7;
    const ushort* src = gsrc + (size_t)row * stride_elems + ((c ^ (row & 7)) << 3);
    gload_lds16(src, lds + (size_t)(j * 256 + wv * 64) * 8);
  }
}

DEVI s16x8 frag_swz(const ushort* lds_tile, int row, int chunk) {
  const int off = row * 128 + ((chunk ^ (row & 7)) << 4);
  return *(const s16x8*)((const char*)lds_tile + off);
}

// ---------------- elementwise cast ----------------
__global__ __launch_bounds__(256) void cast_bf16_k(const float* __restrict__ in,
                                                   ushort* __restrict__ out, int n) {
  int i = (blockIdx.x * 256 + threadIdx.x) * 4;
  if (i >= n) return;
  float4 v = *(const float4*)(in + i);
  ushort4 o;
  o.x = f2bf(v.x); o.y = f2bf(v.y); o.z = f2bf(v.z); o.w = f2bf(v.w);
  *(ushort4*)(out + i) = o;
}

// ---------------- transpose + cast: in (R,C) f32 -> out (C,R) bf16 ----------------
__global__ __launch_bounds__(256) void transpose_cast_k(const float* __restrict__ in,
                                                        ushort* __restrict__ out, int R, int C) {
  __shared__ ushort tile[64][66];
  const int r0 = blockIdx.y * 64, c0 = blockIdx.x * 64;
  const int tid = threadIdx.x;
  #pragma unroll
  for (int j = 0; j < 16; ++j) {
    int idx = j * 256 + tid;
    int r = idx >> 6, c = idx & 63;
    tile[c][r] = f2bf(in[(size_t)(r0 + r) * C + c0 + c]);
  }
  __syncthreads();
  #pragma unroll
  for (int j = 0; j < 16; ++j) {
    int idx = j * 256 + tid;
    int c = idx >> 6, r = idx & 63;
    out[(size_t)(c0 + c) * R + r0 + r] = tile[c][r];
  }
}

// ---------------- RoPE tables ----------------
__global__ __launch_bounds__(256) void rope_table_k(float2* __restrict__ tab) {
  int idx = blockIdx.x * 256 + threadIdx.x;   // T*32 = 65536
  int t = idx >> 5, i = idx & 31;
  float inv = expf(-(float)i * 0.28782313662425575f);  // ln(10000)/32
  float ang = (float)t * inv;
  tab[idx] = make_float2(cosf(ang), sinf(ang));
}

// =====================================================================
// Fused QKV GEMM, 256x256 4-phase schedule, NON-TEMPLATE.
// Round-5 lesson: amdgpu_waves_per_eu is silently DROPPED on template
// kernels (VGPR pinned 128 + full spill); on plain __global__ functions it
// works (round-4 gemm_bt_8ph: 160 -> ~84 us).  So this is a concrete fn.
// M=4096, N=3072, K=2048.  8 waves (2Mx4N), wave tile 128x64, BK=64,
// double-buffered LDS (128 KiB), counted vmcnt(6), builtin barriers,
// setprio on MFMA, XOR-swizzled LDS, bijective XCD swizzle (NWG=192).
// Epilogue: RoPE in-register + Qp/Kp/Vp fragment pack (bit-verified r1-3).
// =====================================================================
__global__ __attribute__((amdgpu_flat_work_group_size(512, 512)))
__attribute__((amdgpu_waves_per_eu(2, 2)))
void gemm_qkv_8ph(const ushort* __restrict__ A,
                  const ushort* __restrict__ BT,
                  const float2* __restrict__ tab,
                  ushort* __restrict__ Qp,
                  ushort* __restrict__ Kp,
                  ushort* __restrict__ Vp) {
  constexpr int K = 2048;
  constexpr int NKT = K / 64;           // 32
  constexpr int GX = 12;                // N=3072
  constexpr int NWG = 192;
  __shared__ __attribute__((aligned(128))) ushort smem[65536];   // 128 KiB

  const int tid = threadIdx.x;
  const int ln = tid & 63, wv = tid >> 6;
  const int g = ln >> 4, l15 = ln & 15, l31 = ln & 31, hi = ln >> 5;
  const int wm = wv >> 2, wn = wv & 3;
  const int wub = tid & ~63;

  const int orig = blockIdx.x;
  const int wg = (orig & 7) * (NWG / 8) + (orig >> 3);   // bijective XCD swizzle
  const int bx = wg % GX, by = wg / GX;
  const int m0 = by * 256, n0 = bx * 256;

  ushort* Asm = smem;                   // [buf][half][128*64]
  ushort* Bsm = smem + 32768;

  auto stageA = [&](int t, int h) {
    const ushort* gs = A + (size_t)(m0 + h * 128) * K + t * 64;
    ushort* ld = Asm + (t & 1) * 16384 + h * 8192;
    #pragma unroll
    for (int j = 0; j < 2; ++j) {
      int ci = j * 512 + tid;
      int row = ci >> 3, c = ci & 7;
      gload_lds16(gs + (size_t)row * K + ((c ^ (row & 7)) << 3),
                  ld + (size_t)(j * 512 + wub) * 8);
    }
  };
  auto stageB = [&](int t, int h) {
    const ushort* gs = BT + (size_t)(n0 + h * 128) * K + t * 64;
    ushort* ld = Bsm + (t & 1) * 16384 + h * 8192;
    #pragma unroll
    for (int j = 0; j < 2; ++j) {
      int ci = j * 512 + tid;
      int row = ci >> 3, c = ci & 7;
      gload_lds16(gs + (size_t)row * K + ((c ^ (row & 7)) << 3),
                  ld + (size_t)(j * 512 + wub) * 8);
    }
  };
  auto ldfrag = [&](const ushort* half, int row, int kc) -> s16x8 {
    return *(const s16x8*)((const char*)half + row * 128 + ((kc ^ (row & 7)) << 4));
  };

  f32x4 acc[8][4];
  #pragma unroll
  for (int i = 0; i < 8; ++i)
    #pragma unroll
    for (int j = 0; j < 4; ++j) acc[i][j] = (f32x4){0.f, 0.f, 0.f, 0.f};

  // ---- prologue: tile0 full + tile1 {B0,B1,A0} ----
  stageB(0, 0); stageB(0, 1); stageA(0, 0); stageA(0, 1);
  stageB(1, 0); stageB(1, 1); stageA(1, 0);
  asm volatile("s_waitcnt vmcnt(6)" ::: "memory");
  SBAR();

  #pragma unroll 1
  for (int t = 0; t < NKT; ++t) {
    const ushort* Ah = Asm + (t & 1) * 16384 + wm * 8192;
    const ushort* Bh = Bsm + (t & 1) * 16384 + (wn >> 1) * 8192;
    s16x8 af[4][2], bfr[4][2];

    // ---- q0: read all B + A-low; stage (t+1).A1; MFMA a0*b01 ----
    #pragma unroll
    for (int ks = 0; ks < 2; ++ks) {
      #pragma unroll
      for (int ni = 0; ni < 4; ++ni)
        bfr[ni][ks] = ldfrag(Bh, (wn & 1) * 64 + ni * 16 + l15, ks * 4 + g);
      #pragma unroll
      for (int mi = 0; mi < 4; ++mi)
        af[mi][ks] = ldfrag(Ah, mi * 16 + l15, ks * 4 + g);
    }
    if (t + 1 < NKT) stageA(t + 1, 1);
    SBAR();
    LGKM0();
    __builtin_amdgcn_s_setprio(1);
    #pragma unroll
    for (int mi = 0; mi < 4; ++mi)
      #pragma unroll
      for (int ni = 0; ni < 2; ++ni)
        #pragma unroll
        for (int ks = 0; ks < 2; ++ks)
          acc[mi][ni] = MFMA16(af[mi][ks], bfr[ni][ks], acc[mi][ni], 0, 0, 0);
    __builtin_amdgcn_s_setprio(0);
    SBAR();

    // ---- q1: stage (t+2).B0; MFMA a0*b23 ----
    if (t + 2 < NKT) stageB(t + 2, 0);
    SBAR();
    __builtin_amdgcn_s_setprio(1);
    #pragma unroll
    for (int mi = 0; mi < 4; ++mi)
      #pragma unroll
      for (int ni = 0; ni < 2; ++ni)
        #pragma unroll
        for (int ks = 0; ks < 2; ++ks)
          acc[mi][2 + ni] = MFMA16(af[mi][ks], bfr[2 + ni][ks], acc[mi][2 + ni], 0, 0, 0);
    __builtin_amdgcn_s_setprio(0);
    SBAR();

    // ---- q2: read A-high (reuse af); stage (t+2).B1; MFMA a1*b01 ----
    #pragma unroll
    for (int ks = 0; ks < 2; ++ks)
      #pragma unroll
      for (int mi = 0; mi < 4; ++mi)
        af[mi][ks] = ldfrag(Ah, 64 + mi * 16 + l15, ks * 4 + g);
    if (t + 2 < NKT) stageB(t + 2, 1);
    SBAR();
    LGKM0();
    __builtin_amdgcn_s_setprio(1);
    #pragma unroll
    for (int mi = 0; mi < 4; ++mi)
      #pragma unroll
      for (int ni = 0; ni < 2; ++ni)
        #pragma unroll
        for (int ks = 0; ks < 2; ++ks)
          acc[4 + mi][ni] = MFMA16(af[mi][ks], bfr[ni][ks], acc[4 + mi][ni], 0, 0, 0);
    __builtin_amdgcn_s_setprio(0);
    SBAR();

    // ---- q3: stage (t+2).A0; MFMA a1*b23; counted vmcnt ----
    if (t + 2 < NKT) stageA(t + 2, 0);
    SBAR();
    __builtin_amdgcn_s_setprio(1);
    #pragma unroll
    for (int mi = 0; mi < 4; ++mi)
      #pragma unroll
      for (int ni = 0; ni < 2; ++ni)
        #pragma unroll
        for (int ks = 0; ks < 2; ++ks)
          acc[4 + mi][2 + ni] = MFMA16(af[mi][ks], bfr[2 + ni][ks], acc[4 + mi][2 + ni], 0, 0, 0);
    __builtin_amdgcn_s_setprio(0);
    if (t + 2 < NKT)      asm volatile("s_waitcnt vmcnt(6)" ::: "memory");
    else if (t + 1 < NKT) asm volatile("s_waitcnt vmcnt(0)" ::: "memory");
    SBAR();
  }

  // ---- RoPE epilogue + fragment pack (two 128-row passes through LDS) ----
  const int bq = by >> 3;              // batch
  const int tb0 = (by & 7) * 256;      // batch-local row base of this block
  const int type = (bx < 8) ? 0 : (bx < 10 ? 1 : 2);   // Q / K / V per block
  constexpr int OST = 260;             // Ot stride (elements)

  __syncthreads();                     // all waves out of the K-loop
  #pragma unroll 1
  for (int hm = 0; hm < 2; ++hm) {
    if (wm == hm) {
      #pragma unroll
      for (int mi = 0; mi < 8; ++mi)
        #pragma unroll
        for (int r = 0; r < 4; ++r) {
          const int tl = mi * 16 + g * 4 + r;
          const int t = tb0 + hm * 128 + tl;
          #pragma unroll
          for (int ni = 0; ni < 4; ++ni) {
            const int cl = wn * 64 + ni * 16 + l15;
            float val = acc[mi][ni][r], outv;
            if (type < 2) {
              float pairv = acc[mi][ni ^ 2][r];
              float2 cs = tab[t * 32 + (ni & 1) * 16 + l15];
              outv = (ni & 2) ? (val * cs.x + pairv * cs.y) : (val * cs.x - pairv * cs.y);
              if (type == 0) outv *= 0.18033688011112042f;   // 0.125 * log2(e)
            } else {
              outv = val;
            }
            smem[tl * OST + cl] = f2bf(outv);
          }
        }
    }
    __syncthreads();
    // 64 chunks for this 128-row half: id = wv*8+it
    #pragma unroll
    for (int it = 0; it < 8; ++it) {
      const int id = wv * 8 + it;
      const int hl = id >> 4, q4 = (id >> 2) & 3, fi = id & 3;
      const int tile = (by & 7) * 8 + hm * 4 + q4;
      if (type < 2) {
        const ushort* srow = smem + (q4 * 32 + l31) * OST + hl * 64 + fi * 16 + hi * 8;
        union { s16x4 h[2]; s16x8 v; } u;
        u.h[0] = *(const s16x4*)srow;
        u.h[1] = *(const s16x4*)(srow + 4);
        ushort* dst;
        if (type == 0) {
          const int h = bx * 4 + hl;
          dst = Qp + (((size_t)(bq * 32 + h) * 64 + tile) * 4 + fi) * 512 + ln * 8;
        } else {
          const int h = (bx - 8) * 4 + hl;
          dst = Kp + (((size_t)(bq * 8 + h) * 64 + tile) * 4 + fi) * 512 + ln * 8;
        }
        *(s16x8*)dst = u.v;
      } else {
        const int hk = (bx - 10) * 4 + hl;
        const int col = hl * 64 + (fi & 1) * 32 + l31;
        const int row0 = q4 * 32 + (fi >> 1) * 16 + hi * 8;
        union { ushort o[8]; s16x8 v; } u;
        #pragma unroll
        for (int j2 = 0; j2 < 8; ++j2) u.o[j2] = smem[(row0 + j2) * OST + col];
        ushort* dst = Vp + (((size_t)(bq * 8 + hk) * 64 + tile) * 4 + fi) * 512 + ln * 8;
        *(s16x8*)dst = u.v;
      }
    }
    __syncthreads();
  }
}

// ---------------- GEMM: C(M,N) f32 = A(M,K) bf16 @ BT(N,K)^T bf16 ----------------
// Round-0 proven 128x128 m97-structure (full-chip 512-block grid for Wo).
__global__ __launch_bounds__(256) void gemm_bt(const ushort* __restrict__ A,
                                               const ushort* __restrict__ BT,
                                               float* __restrict__ C, int M, int N, int K) {
  __shared__ __align__(128) ushort As[128 * 64];
  __shared__ __align__(128) ushort Bs[128 * 64];
  const int tid = threadIdx.x;
  const int ln = tid & 63, wv = tid >> 6;
  const int g = ln >> 4, l15 = ln & 15;
  const int wm = wv >> 1, wn = wv & 1;
  const int m0 = blockIdx.y * 128, n0 = blockIdx.x * 128;

  f32x4 zero = {0.f, 0.f, 0.f, 0.f};
  f32x4 acc[4][4];
  #pragma unroll
  for (int i = 0; i < 4; ++i)
    #pragma unroll
    for (int j = 0; j < 4; ++j) acc[i][j] = zero;

  for (int kt = 0; kt < K; kt += 64) {
    __syncthreads();
    stage_swz<4>(A + (size_t)m0 * K + kt, K, As, tid);
    stage_swz<4>(BT + (size_t)n0 * K + kt, K, Bs, tid);
    __syncthreads();
    #pragma unroll
    for (int ks = 0; ks < 2; ++ks) {
      s16x8 af[4], bfr[4];
      #pragma unroll
      for (int mi = 0; mi < 4; ++mi) af[mi] = frag_swz(As, wm * 64 + mi * 16 + l15, ks * 4 + g);
      #pragma unroll
      for (int ni = 0; ni < 4; ++ni) bfr[ni] = frag_swz(Bs, wn * 64 + ni * 16 + l15, ks * 4 + g);
      #pragma unroll
      for (int mi = 0; mi < 4; ++mi)
        #pragma unroll
        for (int ni = 0; ni < 4; ++ni)
          acc[mi][ni] = __builtin_amdgcn_mfma_f32_16x16x32_bf16(af[mi], bfr[ni], acc[mi][ni], 0, 0, 0);
    }
  }
  #pragma unroll
  for (int mi = 0; mi < 4; ++mi)
    #pragma unroll
    for (int r = 0; r < 4; ++r) {
      int row = m0 + wm * 64 + mi * 16 + g * 4 + r;
      float* crow = C + (size_t)row * N + n0 + wn * 64 + l15;
      #pragma unroll
      for (int ni = 0; ni < 4; ++ni) crow[ni * 16] = acc[mi][ni][r];
    }
}

// ---------------- causal GQA flash attention, swapped-QK^T 32x32, barrier-free ----------------
__global__ __launch_bounds__(256) void attn_k(const ushort* __restrict__ Qp,
                                              const ushort* __restrict__ Kp,
                                              const ushort* __restrict__ Vp,
                                              ushort* __restrict__ O) {
  __shared__ ushort ep[4][32 * 64];   // per-wave epilogue transpose patch
  const int tid = threadIdx.x, wv = tid >> 6, ln = tid & 63;
  const int l31 = ln & 31, hi = ln >> 5;

  const int f = blockIdx.x + gridDim.x * (blockIdx.y + 32 * blockIdx.z);  // 0..1023
  const int xcd = f & 7, j = f >> 3;         // j: 0..127
  const int pr = xcd + 8 * (j & 1);          // (b,hk) pair id, 0..15
  const int b = pr >> 3, hk = pr & 7;
  const int s = j >> 1;                      // 0..63
  const int hq = hk * 4 + (s & 3);
  const int qtile = 63 - ((s >> 2) * 4 + wv);   // LJF
  const int qw = qtile * 32;
  const int nt = qtile + 1;

  const ushort* Qh    = Qp + ((size_t)(b * 32 + hq)) * (64 * 2048);
  const ushort* Kbase = Kp + ((size_t)(b * 8 + hk)) * (64 * 2048);
  const ushort* Vbase = Vp + ((size_t)(b * 8 + hk)) * (64 * 2048);
  ushort* lds = ep[wv];

  s16x8 qf[4];
  {
    const ushort* qp_ = Qh + (size_t)qtile * 2048 + ln * 8;
    #pragma unroll
    for (int ks = 0; ks < 4; ++ks) qf[ks] = *(const s16x8*)(qp_ + ks * 512);
  }

  f32x16 oacc[2];
  #pragma unroll
  for (int dt = 0; dt < 2; ++dt)
    #pragma unroll
    for (int r = 0; r < 16; ++r) oacc[dt][r] = 0.f;
  float m = -1e30f, l = 0.f;

  const ushort* kp = Kbase + ln * 8;
  const ushort* vp = Vbase + ln * 8;

  s16x8 kf[4];
  #pragma unroll
  for (int ks = 0; ks < 4; ++ks) kf[ks] = *(const s16x8*)(kp + ks * 512);
  kp += 2048;

  s16x8 vc[4];
  union pfu { unsigned u[4]; s16x8 v; };
  pfu pf0, pf1;

  #pragma unroll 1
  for (int kt = 0; kt < nt; ++kt) {
    if (kt) {
      __builtin_amdgcn_s_setprio(1);
      oacc[0] = __builtin_amdgcn_mfma_f32_32x32x16_bf16(vc[0], pf0.v, oacc[0], 0, 0, 0);
      oacc[1] = __builtin_amdgcn_mfma_f32_32x32x16_bf16(vc[1], pf0.v, oacc[1], 0, 0, 0);
      oacc[0] = __builtin_amdgcn_mfma_f32_32x32x16_bf16(vc[2], pf1.v, oacc[0], 0, 0, 0);
      oacc[1] = __builtin_amdgcn_mfma_f32_32x32x16_bf16(vc[3], pf1.v, oacc[1], 0, 0, 0);
      __builtin_amdgcn_s_setprio(0);
    }
    #pragma unroll
    for (int fi2 = 0; fi2 < 4; ++fi2) vc[fi2] = *(const s16x8*)(vp + fi2 * 512);
    vp += 2048;

    f32x16 sp;
    #pragma unroll
    for (int r = 0; r < 16; ++r) sp[r] = 0.f;
    __builtin_amdgcn_s_setprio(1);
    #pragma unroll
    for (int ks = 0; ks < 4; ++ks)
      sp = __builtin_amdgcn_mfma_f32_32x32x16_bf16(kf[ks], qf[ks], sp, 0, 0, 0);
    __builtin_amdgcn_s_setprio(0);

    if (kt + 1 < nt) {
      #pragma unroll
      for (int ks = 0; ks < 4; ++ks) kf[ks] = *(const s16x8*)(kp + ks * 512);
      kp += 2048;
    }

    if (kt == qtile) {
      #pragma unroll
      for (int r = 0; r < 16; ++r) {
        int key = (r & 3) + 8 * (r >> 2) + 4 * hi;
        if (key > l31) sp[r] = -1e30f;
      }
    }

    float t0 = fmaxf(fmaxf(sp[0], sp[1]), sp[2]);
    float t1 = fmaxf(fmaxf(sp[3], sp[4]), sp[5]);
    float t2 = fmaxf(fmaxf(sp[6], sp[7]), sp[8]);
    float t3 = fmaxf(fmaxf(sp[9], sp[10]), sp[11]);
    float t4 = fmaxf(fmaxf(sp[12], sp[13]), sp[14]);
    float u0 = fmaxf(fmaxf(t0, t1), t2);
    float u1 = fmaxf(fmaxf(t3, t4), sp[15]);
    float pm = fmaxf(u0, u1);
    pm = fmaxf(pm, __shfl_xor(pm, 32, 64));

    if (__any(pm > m)) {
      float mn = fmaxf(m, pm);
      float alpha = __builtin_amdgcn_exp2f(m - mn);
      m = mn;
      l *= alpha;
      #pragma unroll
      for (int dt = 0; dt < 2; ++dt)
        #pragma unroll
        for (int r = 0; r < 16; ++r) oacc[dt][r] *= alpha;
    }

    #pragma unroll
    for (int r = 0; r < 16; ++r) sp[r] = __builtin_amdgcn_exp2f(sp[r] - m);
    {
      float a0 = sp[0] + sp[1], a1 = sp[2] + sp[3], a2 = sp[4] + sp[5], a3 = sp[6] + sp[7];
      float a4 = sp[8] + sp[9], a5 = sp[10] + sp[11], a6 = sp[12] + sp[13], a7 = sp[14] + sp[15];
      float b0 = a0 + a1, b1 = a2 + a3, b2 = a4 + a5, b3 = a6 + a7;
      float rs = (b0 + b1) + (b2 + b3);
      rs += __shfl_xor(rs, 32, 64);
      l += rs;
    }

    unsigned cw[8], xs[8];
    #pragma unroll
    for (int jj = 0; jj < 8; ++jj) {
      union { __hip_bfloat162 h; unsigned u; } pk;
      pk.h = __float22bfloat162_rn(make_float2(sp[2 * jj], sp[2 * jj + 1]));
      cw[jj] = pk.u;
    }
    #pragma unroll
    for (int jj = 0; jj < 8; ++jj) xs[jj] = __shfl_xor(cw[jj], 32, 64);
    pf0.u[0] = hi ? xs[2] : cw[0];
    pf0.u[1] = hi ? xs[3] : cw[1];
    pf0.u[2] = hi ? cw[2] : xs[0];
    pf0.u[3] = hi ? cw[3] : xs[1];
    pf1.u[0] = hi ? xs[6] : cw[4];
    pf1.u[1] = hi ? xs[7] : cw[5];
    pf1.u[2] = hi ? cw[6] : xs[4];
    pf1.u[3] = hi ? cw[7] : xs[5];
  }

  __builtin_amdgcn_s_setprio(1);
  oacc[0] = __builtin_amdgcn_mfma_f32_32x32x16_bf16(vc[0], pf0.v, oacc[0], 0, 0, 0);
  oacc[1] = __builtin_amdgcn_mfma_f32_32x32x16_bf16(vc[1], pf0.v, oacc[1], 0, 0, 0);
  oacc[0] = __builtin_amdgcn_mfma_f32_32x32x16_bf16(vc[2], pf1.v, oacc[0], 0, 0, 0);
  oacc[1] = __builtin_amdgcn_mfma_f32_32x32x16_bf16(vc[3], pf1.v, oacc[1], 0, 0, 0);
  __builtin_amdgcn_s_setprio(0);

  float invl = 1.0f / l;
  #pragma unroll
  for (int dt = 0; dt < 2; ++dt)
    #pragma unroll
    for (int r = 0; r < 16; ++r) {
      int d = dt * 32 + (r & 3) + 8 * (r >> 2) + 4 * hi;
      int byte = (l31 * 128 + d * 2) ^ ((l31 & 7) << 4);
      *(ushort*)((char*)lds + byte) = f2bf(oacc[dt][r] * invl);
    }
  const int qr = ln >> 1, half = ln & 1;
  #pragma unroll
  for (int jj = 0; jj < 4; ++jj) {
    int byte = (qr * 128 + half * 64 + jj * 16) ^ ((qr & 7) << 4);
    s16x8 vrow = *(const s16x8*)((const char*)lds + byte);
    *(s16x8*)(O + ((size_t)(b * 2048 + qw + qr)) * 2048 + hq * 64 + half * 32 + jj * 8) = vrow;
  }
}

extern "C" void kernel_launch(void* const* d_in, const int* in_sizes, int n_in,
                              void* d_out, int out_size, void* d_ws, size_t ws_size,
                              hipStream_t stream) {
  const float* x   = (const float*)d_in[0];
  const float* Wq  = (const float*)d_in[1];
  const float* Wkv = (const float*)d_in[2];
  const float* Wo  = (const float*)d_in[3];
  float* out = (float*)d_out;

  char* ws = (char*)d_ws;
  ushort* xb     = (ushort*)(ws);                 // 16 MiB  x bf16 (4096x2048)
  ushort* WqkvT  = (ushort*)(ws + 16777216);      // 12 MiB  [Wq|Wkv]^T bf16 (3072x2048)
  ushort* WoT    = (ushort*)(ws + 29360128);      //  8 MiB  Wo^T bf16 (2048x2048)
  float2* tab    = (float2*)(ws + 37748736);      // 512 KiB rope tables
  ushort* Qp     = (ushort*)(ws + 38273024);      // 16 MiB  Q packed
  ushort* Kp     = (ushort*)(ws + 55050240);      //  4 MiB  K packed
  ushort* Vp     = (ushort*)(ws + 59244544);      //  4 MiB  V packed
  ushort* Ob     = (ushort*)(ws + 63438848);      // 16 MiB  attn out bf16 (4096x2048)

  cast_bf16_k<<<8192, 256, 0, stream>>>(x, xb, 2 * 2048 * 2048);
  transpose_cast_k<<<dim3(32, 32), 256, 0, stream>>>(Wq, WqkvT, 2048, 2048);
  transpose_cast_k<<<dim3(16, 32), 256, 0, stream>>>(Wkv, WqkvT + 2048 * 2048, 2048, 1024);
  transpose_cast_k<<<dim3(32, 32), 256, 0, stream>>>(Wo, WoT, 2048, 2048);
  rope_table_k<<<256, 256, 0, stream>>>(tab);
  gemm_qkv_8ph<<<192, 512, 0, stream>>>(xb, WqkvT, tab, Qp, Kp, Vp);
  attn_k<<<dim3(16, 32, 2), 256, 0, stream>>>(Qp, Kp, Vp, Ob);
  gemm_bt<<<dim3(16, 32), 256, 0, stream>>>(Ob, WoT, out, 4096, 2048, 2048);
}

// Round 7
// 235.453 us; speedup vs baseline: 1.3474x; 1.2850x over previous
//
#include <hip/hip_runtime.h>
#include <hip/hip_bf16.h>

#define DEVI __device__ __forceinline__

typedef __attribute__((ext_vector_type(4))) float f32x4;
typedef __attribute__((ext_vector_type(16))) float f32x16;
typedef __attribute__((ext_vector_type(8))) short s16x8;
typedef __attribute__((ext_vector_type(4))) short s16x4;

DEVI ushort f2bf(float f) {
  union { float f; unsigned u; } v; v.f = f;
  unsigned r = v.u + 0x7FFFu + ((v.u >> 16) & 1u);
  return (ushort)(r >> 16);
}

DEVI void gload_lds16(const void* g, void* l) {
  __builtin_amdgcn_global_load_lds((const __attribute__((address_space(1))) void*)g,
                                   (__attribute__((address_space(3))) void*)l, 16, 0, 0);
}

#define MFMA16 __builtin_amdgcn_mfma_f32_16x16x32_bf16
#define SBAR() __builtin_amdgcn_s_barrier()
#define LGKM0() asm volatile("s_waitcnt lgkmcnt(0)")

// Stage one 128x64 bf16 tile (16KB = 1024 chunks) with 512 threads: 2 chunks each.
// Pre-swizzled global source + linear LDS dest (rule #21 pairing with ldfrag).
DEVI void stage128(const ushort* __restrict__ gsrc, int K, ushort* ld, int tid) {
  #pragma unroll
  for (int j = 0; j < 2; ++j) {
    const int ci = j * 512 + tid;
    const int row = ci >> 3, c = ci & 7;
    gload_lds16(gsrc + (size_t)row * K + ((c ^ (row & 7)) << 3),
                ld + (size_t)(j * 512 + (tid & ~63)) * 8);
  }
}

DEVI s16x8 ldfrag(const ushort* tile, int row, int kc) {
  return *(const s16x8*)((const char*)tile + row * 128 + ((kc ^ (row & 7)) << 4));
}

// ---------------- elementwise cast ----------------
__global__ __launch_bounds__(256) void cast_bf16_k(const float* __restrict__ in,
                                                   ushort* __restrict__ out, int n) {
  int i = (blockIdx.x * 256 + threadIdx.x) * 4;
  if (i >= n) return;
  float4 v = *(const float4*)(in + i);
  ushort4 o;
  o.x = f2bf(v.x); o.y = f2bf(v.y); o.z = f2bf(v.z); o.w = f2bf(v.w);
  *(ushort4*)(out + i) = o;
}

// ---------------- transpose + cast: in (R,C) f32 -> out (C,R) bf16 ----------------
__global__ __launch_bounds__(256) void transpose_cast_k(const float* __restrict__ in,
                                                        ushort* __restrict__ out, int R, int C) {
  __shared__ ushort tile[64][66];
  const int r0 = blockIdx.y * 64, c0 = blockIdx.x * 64;
  const int tid = threadIdx.x;
  #pragma unroll
  for (int j = 0; j < 16; ++j) {
    int idx = j * 256 + tid;
    int r = idx >> 6, c = idx & 63;
    tile[c][r] = f2bf(in[(size_t)(r0 + r) * C + c0 + c]);
  }
  __syncthreads();
  #pragma unroll
  for (int j = 0; j < 16; ++j) {
    int idx = j * 256 + tid;
    int c = idx >> 6, r = idx & 63;
    out[(size_t)(c0 + c) * R + r0 + r] = tile[c][r];
  }
}

// ---------------- RoPE tables ----------------
__global__ __launch_bounds__(256) void rope_table_k(float2* __restrict__ tab) {
  int idx = blockIdx.x * 256 + threadIdx.x;   // T*32 = 65536
  int t = idx >> 5, i = idx & 31;
  float inv = expf(-(float)i * 0.28782313662425575f);  // ln(10000)/32
  float ang = (float)t * inv;
  tab[idx] = make_float2(cosf(ang), sinf(ang));
}

// =====================================================================
// 2-phase counted-vmcnt K-loop, BM=128 x BN=256 x BK=64, 512 thr / 8 waves
// (2M x 4N), wave tile 64x64 -> acc[4][4]=64 VGPR + frags 64: fits the
// 128-arch + 64-AGPR budget the allocator actually gives (rounds 1-6: the
// 128x64 wave tile / acc=128 geometry ALWAYS spilled ~120MB, no attribute
// could lift the 128-reg target).  LDS 96 KiB dbuf.  Per iter:
//   q0: 16 ds_read frags; BAR; lgkm0+sched_bar; prio1 MFMA b01 x16; BAR
//   q1: stage A(t+1)[2] + B(t+2)[4]; prio1 MFMA b23 x16; vmcnt(4); BAR
// vmcnt(4) leaves only B(t+2) in flight -> A(t+1),B(t+1) complete at BAR.
// B(t+2) overwrites the currently-read buffer, legal: issued after q0-exit
// barrier (every wave lgkm-drained its reads before its q0 MFMA).
// =====================================================================
DEVI void kloop_2ph(const ushort* __restrict__ A, const ushort* __restrict__ BT,
                    ushort* Asm, ushort* Bsm, int m0, int n0, int K, int NKT,
                    f32x4 (&acc)[4][4], int tid, int wm, int wn, int g, int l15) {
  // prologue: A(0), B(0,0), B(0,1)  then  B(1,0), B(1,1)
  stage128(A + (size_t)m0 * K, K, Asm, tid);
  stage128(BT + (size_t)n0 * K, K, Bsm, tid);
  stage128(BT + (size_t)(n0 + 128) * K, K, Bsm + 8192, tid);
  stage128(BT + (size_t)n0 * K + 64, K, Bsm + 16384, tid);
  stage128(BT + (size_t)(n0 + 128) * K + 64, K, Bsm + 16384 + 8192, tid);
  asm volatile("s_waitcnt vmcnt(4)");
  SBAR();

  #pragma unroll 1
  for (int t = 0; t < NKT; ++t) {
    const ushort* Ah = Asm + (t & 1) * 8192;
    const ushort* Bh = Bsm + (t & 1) * 16384;
    s16x8 af[4][2], bfr[4][2];

    // ---- q0: read all frags; MFMA b01 ----
    #pragma unroll
    for (int ks = 0; ks < 2; ++ks) {
      #pragma unroll
      for (int ni = 0; ni < 4; ++ni)
        bfr[ni][ks] = ldfrag(Bh, wn * 64 + ni * 16 + l15, ks * 4 + g);
      #pragma unroll
      for (int mi = 0; mi < 4; ++mi)
        af[mi][ks] = ldfrag(Ah, wm * 64 + mi * 16 + l15, ks * 4 + g);
    }
    SBAR();
    LGKM0();
    __builtin_amdgcn_sched_barrier(0);
    __builtin_amdgcn_s_setprio(1);
    #pragma unroll
    for (int mi = 0; mi < 4; ++mi)
      #pragma unroll
      for (int ni = 0; ni < 2; ++ni)
        #pragma unroll
        for (int ks = 0; ks < 2; ++ks)
          acc[mi][ni] = MFMA16(af[mi][ks], bfr[ni][ks], acc[mi][ni], 0, 0, 0);
    __builtin_amdgcn_s_setprio(0);
    SBAR();

    // ---- q1: stage next tiles; MFMA b23; counted vmcnt ----
    if (t + 1 < NKT)
      stage128(A + (size_t)m0 * K + (t + 1) * 64, K, Asm + ((t + 1) & 1) * 8192, tid);
    if (t + 2 < NKT) {
      stage128(BT + (size_t)n0 * K + (t + 2) * 64, K, Bsm + (t & 1) * 16384, tid);
      stage128(BT + (size_t)(n0 + 128) * K + (t + 2) * 64, K, Bsm + (t & 1) * 16384 + 8192, tid);
    }
    __builtin_amdgcn_s_setprio(1);
    #pragma unroll
    for (int mi = 0; mi < 4; ++mi)
      #pragma unroll
      for (int ni = 0; ni < 2; ++ni)
        #pragma unroll
        for (int ks = 0; ks < 2; ++ks)
          acc[mi][2 + ni] = MFMA16(af[mi][ks], bfr[2 + ni][ks], acc[mi][2 + ni], 0, 0, 0);
    __builtin_amdgcn_s_setprio(0);
    if (t + 2 < NKT)      asm volatile("s_waitcnt vmcnt(4)");
    else if (t + 1 < NKT) asm volatile("s_waitcnt vmcnt(0)");
    SBAR();
  }
}

// ---------------- fused QKV GEMM: M=4096, N=3072, K=2048, grid 384 ----------------
__global__ __launch_bounds__(512) void gemm_qkv_w2(const ushort* __restrict__ A,
                                                   const ushort* __restrict__ BT,
                                                   const float2* __restrict__ tab,
                                                   ushort* __restrict__ Qp,
                                                   ushort* __restrict__ Kp,
                                                   ushort* __restrict__ Vp) {
  constexpr int K = 2048, NKT = 32, GX = 12, NWG = 384;
  __shared__ __attribute__((aligned(128))) ushort smem[49152];   // 96 KiB
  ushort* Asm = smem;            // [2][128*64]
  ushort* Bsm = smem + 16384;    // [2][2][128*64]

  const int tid = threadIdx.x;
  const int ln = tid & 63, wv = tid >> 6;
  const int g = ln >> 4, l15 = ln & 15, l31 = ln & 31, hi = ln >> 5;
  const int wm = wv >> 2, wn = wv & 3;

  const int orig = blockIdx.x;
  const int wg = (orig & 7) * (NWG / 8) + (orig >> 3);   // bijective XCD swizzle
  const int bx = wg % GX, by = wg / GX;
  const int m0 = by * 128, n0 = bx * 256;

  f32x4 acc[4][4];
  #pragma unroll
  for (int i = 0; i < 4; ++i)
    #pragma unroll
    for (int j = 0; j < 4; ++j) acc[i][j] = (f32x4){0.f, 0.f, 0.f, 0.f};

  kloop_2ph(A, BT, Asm, Bsm, m0, n0, K, NKT, acc, tid, wm, wn, g, l15);

  // ---- RoPE epilogue + fragment pack (single 128x256 LDS pass) ----
  const int bq = by >> 4;               // batch (16 blocks of 128 rows per batch)
  const int tb0 = (by & 15) * 128;      // batch-local row base
  const int type = (bx < 8) ? 0 : (bx < 10 ? 1 : 2);   // Q / K / V per block
  constexpr int OST = 260;              // Ot stride (128*260*2B = 65KB <= 96KB)
  ushort* Ot = smem;

  __syncthreads();
  #pragma unroll
  for (int mi = 0; mi < 4; ++mi)
    #pragma unroll
    for (int r = 0; r < 4; ++r) {
      const int tl = wm * 64 + mi * 16 + g * 4 + r;
      const int t = tb0 + tl;
      #pragma unroll
      for (int ni = 0; ni < 4; ++ni) {
        const int cl = wn * 64 + ni * 16 + l15;
        float val = acc[mi][ni][r], outv;
        if (type < 2) {                  // RoPE (Q and K); wave tile = one head
          float pairv = acc[mi][ni ^ 2][r];
          float2 cs = tab[t * 32 + (ni & 1) * 16 + l15];
          outv = (ni & 2) ? (val * cs.x + pairv * cs.y) : (val * cs.x - pairv * cs.y);
          if (type == 0) outv *= 0.18033688011112042f;   // 0.125 * log2(e)
        } else {
          outv = val;
        }
        Ot[tl * OST + cl] = f2bf(outv);
      }
    }
  __syncthreads();

  // 64 chunks: id = wv*8+it -> hl = id>>4 (head 0-3), q4 = (id>>2)&3, fi = id&3
  #pragma unroll
  for (int it = 0; it < 8; ++it) {
    const int id = wv * 8 + it;
    const int hl = id >> 4, q4 = (id >> 2) & 3, fi = id & 3;
    const int tile = (by & 15) * 4 + q4;
    if (type < 2) {
      const ushort* srow = Ot + (q4 * 32 + l31) * OST + hl * 64 + fi * 16 + hi * 8;
      union { s16x4 h[2]; s16x8 v; } u;
      u.h[0] = *(const s16x4*)srow;
      u.h[1] = *(const s16x4*)(srow + 4);
      ushort* dst;
      if (type == 0) {
        const int h = bx * 4 + hl;
        dst = Qp + (((size_t)(bq * 32 + h) * 64 + tile) * 4 + fi) * 512 + ln * 8;
      } else {
        const int h = (bx - 8) * 4 + hl;
        dst = Kp + (((size_t)(bq * 8 + h) * 64 + tile) * 4 + fi) * 512 + ln * 8;
      }
      *(s16x8*)dst = u.v;
    } else {
      const int hk = (bx - 10) * 4 + hl;
      const int col = hl * 64 + (fi & 1) * 32 + l31;
      const int row0 = q4 * 32 + (fi >> 1) * 16 + hi * 8;
      union { ushort o[8]; s16x8 v; } u;
      #pragma unroll
      for (int j2 = 0; j2 < 8; ++j2) u.o[j2] = Ot[(row0 + j2) * OST + col];
      ushort* dst = Vp + (((size_t)(bq * 8 + hk) * 64 + tile) * 4 + fi) * 512 + ln * 8;
      *(s16x8*)dst = u.v;
    }
  }
}

// ---------------- Wo GEMM: M=4096, N=2048, K=2048, grid 256 = 1 block/CU ----------------
__global__ __launch_bounds__(512) void gemm_wo_w2(const ushort* __restrict__ A,
                                                  const ushort* __restrict__ BT,
                                                  float* __restrict__ C) {
  constexpr int K = 2048, NKT = 32, N = 2048, GX = 8, NWG = 256;
  __shared__ __attribute__((aligned(128))) ushort smem[49152];   // 96 KiB
  ushort* Asm = smem;
  ushort* Bsm = smem + 16384;

  const int tid = threadIdx.x;
  const int ln = tid & 63, wv = tid >> 6;
  const int g = ln >> 4, l15 = ln & 15;
  const int wm = wv >> 2, wn = wv & 3;

  const int orig = blockIdx.x;
  const int wg = (orig & 7) * (NWG / 8) + (orig >> 3);   // bijective XCD swizzle
  const int bx = wg % GX, by = wg / GX;
  const int m0 = by * 128, n0 = bx * 256;

  f32x4 acc[4][4];
  #pragma unroll
  for (int i = 0; i < 4; ++i)
    #pragma unroll
    for (int j = 0; j < 4; ++j) acc[i][j] = (f32x4){0.f, 0.f, 0.f, 0.f};

  kloop_2ph(A, BT, Asm, Bsm, m0, n0, K, NKT, acc, tid, wm, wn, g, l15);

  #pragma unroll
  for (int mi = 0; mi < 4; ++mi)
    #pragma unroll
    for (int r = 0; r < 4; ++r) {
      int row = m0 + wm * 64 + mi * 16 + g * 4 + r;
      float* crow = C + (size_t)row * N + n0 + wn * 64 + l15;
      #pragma unroll
      for (int ni = 0; ni < 4; ++ni) crow[ni * 16] = acc[mi][ni][r];
    }
}

// ---------------- causal GQA flash attention, swapped-QK^T 32x32, barrier-free ----------------
__global__ __launch_bounds__(256) void attn_k(const ushort* __restrict__ Qp,
                                              const ushort* __restrict__ Kp,
                                              const ushort* __restrict__ Vp,
                                              ushort* __restrict__ O) {
  __shared__ ushort ep[4][32 * 64];   // per-wave epilogue transpose patch
  const int tid = threadIdx.x, wv = tid >> 6, ln = tid & 63;
  const int l31 = ln & 31, hi = ln >> 5;

  const int f = blockIdx.x + gridDim.x * (blockIdx.y + 32 * blockIdx.z);  // 0..1023
  const int xcd = f & 7, j = f >> 3;         // j: 0..127
  const int pr = xcd + 8 * (j & 1);          // (b,hk) pair id, 0..15
  const int b = pr >> 3, hk = pr & 7;
  const int s = j >> 1;                      // 0..63
  const int hq = hk * 4 + (s & 3);
  const int qtile = 63 - ((s >> 2) * 4 + wv);   // LJF
  const int qw = qtile * 32;
  const int nt = qtile + 1;

  const ushort* Qh    = Qp + ((size_t)(b * 32 + hq)) * (64 * 2048);
  const ushort* Kbase = Kp + ((size_t)(b * 8 + hk)) * (64 * 2048);
  const ushort* Vbase = Vp + ((size_t)(b * 8 + hk)) * (64 * 2048);
  ushort* lds = ep[wv];

  s16x8 qf[4];
  {
    const ushort* qp_ = Qh + (size_t)qtile * 2048 + ln * 8;
    #pragma unroll
    for (int ks = 0; ks < 4; ++ks) qf[ks] = *(const s16x8*)(qp_ + ks * 512);
  }

  f32x16 oacc[2];
  #pragma unroll
  for (int dt = 0; dt < 2; ++dt)
    #pragma unroll
    for (int r = 0; r < 16; ++r) oacc[dt][r] = 0.f;
  float m = -1e30f, l = 0.f;

  const ushort* kp = Kbase + ln * 8;
  const ushort* vp = Vbase + ln * 8;

  s16x8 kf[4];
  #pragma unroll
  for (int ks = 0; ks < 4; ++ks) kf[ks] = *(const s16x8*)(kp + ks * 512);
  kp += 2048;

  s16x8 vc[4];
  union pfu { unsigned u[4]; s16x8 v; };
  pfu pf0, pf1;

  #pragma unroll 1
  for (int kt = 0; kt < nt; ++kt) {
    if (kt) {
      __builtin_amdgcn_s_setprio(1);
      oacc[0] = __builtin_amdgcn_mfma_f32_32x32x16_bf16(vc[0], pf0.v, oacc[0], 0, 0, 0);
      oacc[1] = __builtin_amdgcn_mfma_f32_32x32x16_bf16(vc[1], pf0.v, oacc[1], 0, 0, 0);
      oacc[0] = __builtin_amdgcn_mfma_f32_32x32x16_bf16(vc[2], pf1.v, oacc[0], 0, 0, 0);
      oacc[1] = __builtin_amdgcn_mfma_f32_32x32x16_bf16(vc[3], pf1.v, oacc[1], 0, 0, 0);
      __builtin_amdgcn_s_setprio(0);
    }
    #pragma unroll
    for (int fi2 = 0; fi2 < 4; ++fi2) vc[fi2] = *(const s16x8*)(vp + fi2 * 512);
    vp += 2048;

    f32x16 sp;
    #pragma unroll
    for (int r = 0; r < 16; ++r) sp[r] = 0.f;
    __builtin_amdgcn_s_setprio(1);
    #pragma unroll
    for (int ks = 0; ks < 4; ++ks)
      sp = __builtin_amdgcn_mfma_f32_32x32x16_bf16(kf[ks], qf[ks], sp, 0, 0, 0);
    __builtin_amdgcn_s_setprio(0);

    if (kt + 1 < nt) {
      #pragma unroll
      for (int ks = 0; ks < 4; ++ks) kf[ks] = *(const s16x8*)(kp + ks * 512);
      kp += 2048;
    }

    if (kt == qtile) {
      #pragma unroll
      for (int r = 0; r < 16; ++r) {
        int key = (r & 3) + 8 * (r >> 2) + 4 * hi;
        if (key > l31) sp[r] = -1e30f;
      }
    }

    float t0 = fmaxf(fmaxf(sp[0], sp[1]), sp[2]);
    float t1 = fmaxf(fmaxf(sp[3], sp[4]), sp[5]);
    float t2 = fmaxf(fmaxf(sp[6], sp[7]), sp[8]);
    float t3 = fmaxf(fmaxf(sp[9], sp[10]), sp[11]);
    float t4 = fmaxf(fmaxf(sp[12], sp[13]), sp[14]);
    float u0 = fmaxf(fmaxf(t0, t1), t2);
    float u1 = fmaxf(fmaxf(t3, t4), sp[15]);
    float pm = fmaxf(u0, u1);
    pm = fmaxf(pm, __shfl_xor(pm, 32, 64));

    if (__any(pm > m)) {
      float mn = fmaxf(m, pm);
      float alpha = __builtin_amdgcn_exp2f(m - mn);
      m = mn;
      l *= alpha;
      #pragma unroll
      for (int dt = 0; dt < 2; ++dt)
        #pragma unroll
        for (int r = 0; r < 16; ++r) oacc[dt][r] *= alpha;
    }

    #pragma unroll
    for (int r = 0; r < 16; ++r) sp[r] = __builtin_amdgcn_exp2f(sp[r] - m);
    {
      float a0 = sp[0] + sp[1], a1 = sp[2] + sp[3], a2 = sp[4] + sp[5], a3 = sp[6] + sp[7];
      float a4 = sp[8] + sp[9], a5 = sp[10] + sp[11], a6 = sp[12] + sp[13], a7 = sp[14] + sp[15];
      float b0 = a0 + a1, b1 = a2 + a3, b2 = a4 + a5, b3 = a6 + a7;
      float rs = (b0 + b1) + (b2 + b3);
      rs += __shfl_xor(rs, 32, 64);
      l += rs;
    }

    unsigned cw[8], xs[8];
    #pragma unroll
    for (int jj = 0; jj < 8; ++jj) {
      union { __hip_bfloat162 h; unsigned u; } pk;
      pk.h = __float22bfloat162_rn(make_float2(sp[2 * jj], sp[2 * jj + 1]));
      cw[jj] = pk.u;
    }
    #pragma unroll
    for (int jj = 0; jj < 8; ++jj) xs[jj] = __shfl_xor(cw[jj], 32, 64);
    pf0.u[0] = hi ? xs[2] : cw[0];
    pf0.u[1] = hi ? xs[3] : cw[1];
    pf0.u[2] = hi ? cw[2] : xs[0];
    pf0.u[3] = hi ? cw[3] : xs[1];
    pf1.u[0] = hi ? xs[6] : cw[4];
    pf1.u[1] = hi ? xs[7] : cw[5];
    pf1.u[2] = hi ? cw[6] : xs[4];
    pf1.u[3] = hi ? cw[7] : xs[5];
  }

  __builtin_amdgcn_s_setprio(1);
  oacc[0] = __builtin_amdgcn_mfma_f32_32x32x16_bf16(vc[0], pf0.v, oacc[0], 0, 0, 0);
  oacc[1] = __builtin_amdgcn_mfma_f32_32x32x16_bf16(vc[1], pf0.v, oacc[1], 0, 0, 0);
  oacc[0] = __builtin_amdgcn_mfma_f32_32x32x16_bf16(vc[2], pf1.v, oacc[0], 0, 0, 0);
  oacc[1] = __builtin_amdgcn_mfma_f32_32x32x16_bf16(vc[3], pf1.v, oacc[1], 0, 0, 0);
  __builtin_amdgcn_s_setprio(0);

  float invl = 1.0f / l;
  #pragma unroll
  for (int dt = 0; dt < 2; ++dt)
    #pragma unroll
    for (int r = 0; r < 16; ++r) {
      int d = dt * 32 + (r & 3) + 8 * (r >> 2) + 4 * hi;
      int byte = (l31 * 128 + d * 2) ^ ((l31 & 7) << 4);
      *(ushort*)((char*)lds + byte) = f2bf(oacc[dt][r] * invl);
    }
  const int qr = ln >> 1, half = ln & 1;
  #pragma unroll
  for (int jj = 0; jj < 4; ++jj) {
    int byte = (qr * 128 + half * 64 + jj * 16) ^ ((qr & 7) << 4);
    s16x8 vrow = *(const s16x8*)((const char*)lds + byte);
    *(s16x8*)(O + ((size_t)(b * 2048 + qw + qr)) * 2048 + hq * 64 + half * 32 + jj * 8) = vrow;
  }
}

extern "C" void kernel_launch(void* const* d_in, const int* in_sizes, int n_in,
                              void* d_out, int out_size, void* d_ws, size_t ws_size,
                              hipStream_t stream) {
  const float* x   = (const float*)d_in[0];
  const float* Wq  = (const float*)d_in[1];
  const float* Wkv = (const float*)d_in[2];
  const float* Wo  = (const float*)d_in[3];
  float* out = (float*)d_out;

  char* ws = (char*)d_ws;
  ushort* xb     = (ushort*)(ws);                 // 16 MiB  x bf16 (4096x2048)
  ushort* WqkvT  = (ushort*)(ws + 16777216);      // 12 MiB  [Wq|Wkv]^T bf16 (3072x2048)
  ushort* WoT    = (ushort*)(ws + 29360128);      //  8 MiB  Wo^T bf16 (2048x2048)
  float2* tab    = (float2*)(ws + 37748736);      // 512 KiB rope tables
  ushort* Qp     = (ushort*)(ws + 38273024);      // 16 MiB  Q packed
  ushort* Kp     = (ushort*)(ws + 55050240);      //  4 MiB  K packed
  ushort* Vp     = (ushort*)(ws + 59244544);      //  4 MiB  V packed
  ushort* Ob     = (ushort*)(ws + 63438848);      // 16 MiB  attn out bf16 (4096x2048)

  cast_bf16_k<<<8192, 256, 0, stream>>>(x, xb, 2 * 2048 * 2048);
  transpose_cast_k<<<dim3(32, 32), 256, 0, stream>>>(Wq, WqkvT, 2048, 2048);
  transpose_cast_k<<<dim3(16, 32), 256, 0, stream>>>(Wkv, WqkvT + 2048 * 2048, 2048, 1024);
  transpose_cast_k<<<dim3(32, 32), 256, 0, stream>>>(Wo, WoT, 2048, 2048);
  rope_table_k<<<256, 256, 0, stream>>>(tab);
  gemm_qkv_w2<<<384, 512, 0, stream>>>(xb, WqkvT, tab, Qp, Kp, Vp);
  attn_k<<<dim3(16, 32, 2), 256, 0, stream>>>(Qp, Kp, Vp, Ob);
  gemm_wo_w2<<<256, 512, 0, stream>>>(Ob, WoT, out);
}

// Round 8
// 232.027 us; speedup vs baseline: 1.3673x; 1.0148x over previous
//
#include <hip/hip_runtime.h>
#include <hip/hip_bf16.h>

#define DEVI __device__ __forceinline__

typedef __attribute__((ext_vector_type(4))) float f32x4;
typedef __attribute__((ext_vector_type(16))) float f32x16;
typedef __attribute__((ext_vector_type(8))) short s16x8;
typedef __attribute__((ext_vector_type(4))) short s16x4;

DEVI ushort f2bf(float f) {
  union { float f; unsigned u; } v; v.f = f;
  unsigned r = v.u + 0x7FFFu + ((v.u >> 16) & 1u);
  return (ushort)(r >> 16);
}

DEVI void gload_lds16(const void* g, void* l) {
  __builtin_amdgcn_global_load_lds((const __attribute__((address_space(1))) void*)g,
                                   (__attribute__((address_space(3))) void*)l, 16, 0, 0);
}

#define MFMA16 __builtin_amdgcn_mfma_f32_16x16x32_bf16
#define SBAR() __builtin_amdgcn_s_barrier()
#define LGKM0() asm volatile("s_waitcnt lgkmcnt(0)")

// Stage one 128x64 bf16 tile (1024 x 16B chunks) with 256 threads: 4 chunks each.
// Pre-swizzled global source + linear LDS dest (rule #21 pairing with ldfrag).
DEVI void stage128q(const ushort* __restrict__ gsrc, int K, ushort* ld, int tid) {
  #pragma unroll
  for (int j = 0; j < 4; ++j) {
    const int ci = j * 256 + tid;
    const int row = ci >> 3, c = ci & 7;
    gload_lds16(gsrc + (size_t)row * K + ((c ^ (row & 7)) << 3),
                ld + (size_t)(j * 256 + (tid & ~63)) * 8);
  }
}

DEVI s16x8 ldfrag(const ushort* tile, int row, int kc) {
  return *(const s16x8*)((const char*)tile + row * 128 + ((kc ^ (row & 7)) << 4));
}

// =====================================================================
// 2-phase counted-vmcnt K-loop, BM=BN=128, BK=64, 256 thr / 4 waves (2x2),
// wave tile 64x64 (acc[4][4]=64 + frags 64 regs: the proven no-spill class).
// LDS 64 KiB dbuf -> 2 blocks/CU (cross-block overlap on top of the pipeline).
// Schedule per iter (validated round 7 at BM=128/BN=256/512thr, 687 TF/CU-eq):
//   q0: 16 ds_read frags; BAR; lgkm0+sched_bar(0); prio1 MFMA b01 x16; BAR
//   q1: stage A(t+1)->alt buf, B(t+2)->current buf; prio1 MFMA b23 x16;
//       vmcnt(4) [B(t+2) stays in flight]; BAR
// B(t+2) overwrite of the currently-read buffer is legal: issued after the
// q0-exit barrier, at which every wave has lgkm-drained its frags to regs.
// Completion chain: tile t's loads drain at iter (t-1)'s vmcnt(4).
// =====================================================================
DEVI void kloop2(const ushort* __restrict__ A, const ushort* __restrict__ BT,
                 ushort* Asm, ushort* Bsm, int m0, int n0, int K, int NKT,
                 f32x4 (&acc)[4][4], int tid, int wm, int wn, int g, int l15) {
  // prologue: A(0)->buf0, B(0)->buf0, B(1)->buf1; A0/B0 must land, B1 may fly
  stage128q(A + (size_t)m0 * K, K, Asm, tid);
  stage128q(BT + (size_t)n0 * K, K, Bsm, tid);
  stage128q(BT + (size_t)n0 * K + 64, K, Bsm + 8192, tid);
  asm volatile("s_waitcnt vmcnt(4)");
  SBAR();

  #pragma unroll 1
  for (int t = 0; t < NKT; ++t) {
    const ushort* Ah = Asm + (t & 1) * 8192;
    const ushort* Bh = Bsm + (t & 1) * 8192;
    s16x8 af[4][2], bfr[4][2];

    // ---- q0: read all frags; MFMA b01 ----
    #pragma unroll
    for (int ks = 0; ks < 2; ++ks) {
      #pragma unroll
      for (int ni = 0; ni < 4; ++ni)
        bfr[ni][ks] = ldfrag(Bh, wn * 64 + ni * 16 + l15, ks * 4 + g);
      #pragma unroll
      for (int mi = 0; mi < 4; ++mi)
        af[mi][ks] = ldfrag(Ah, wm * 64 + mi * 16 + l15, ks * 4 + g);
    }
    SBAR();
    LGKM0();
    __builtin_amdgcn_sched_barrier(0);
    __builtin_amdgcn_s_setprio(1);
    #pragma unroll
    for (int mi = 0; mi < 4; ++mi)
      #pragma unroll
      for (int ni = 0; ni < 2; ++ni)
        #pragma unroll
        for (int ks = 0; ks < 2; ++ks)
          acc[mi][ni] = MFMA16(af[mi][ks], bfr[ni][ks], acc[mi][ni], 0, 0, 0);
    __builtin_amdgcn_s_setprio(0);
    SBAR();

    // ---- q1: stage next tiles; MFMA b23; counted vmcnt ----
    if (t + 1 < NKT)
      stage128q(A + (size_t)m0 * K + (t + 1) * 64, K, Asm + ((t + 1) & 1) * 8192, tid);
    if (t + 2 < NKT)
      stage128q(BT + (size_t)n0 * K + (t + 2) * 64, K, Bsm + (t & 1) * 8192, tid);
    __builtin_amdgcn_s_setprio(1);
    #pragma unroll
    for (int mi = 0; mi < 4; ++mi)
      #pragma unroll
      for (int ni = 0; ni < 2; ++ni)
        #pragma unroll
        for (int ks = 0; ks < 2; ++ks)
          acc[mi][2 + ni] = MFMA16(af[mi][ks], bfr[2 + ni][ks], acc[mi][2 + ni], 0, 0, 0);
    __builtin_amdgcn_s_setprio(0);
    if (t + 2 < NKT)      asm volatile("s_waitcnt vmcnt(4)");
    else if (t + 1 < NKT) asm volatile("s_waitcnt vmcnt(0)");
    SBAR();
  }
}

// ---------------- elementwise cast ----------------
__global__ __launch_bounds__(256) void cast_bf16_k(const float* __restrict__ in,
                                                   ushort* __restrict__ out, int n) {
  int i = (blockIdx.x * 256 + threadIdx.x) * 4;
  if (i >= n) return;
  float4 v = *(const float4*)(in + i);
  ushort4 o;
  o.x = f2bf(v.x); o.y = f2bf(v.y); o.z = f2bf(v.z); o.w = f2bf(v.w);
  *(ushort4*)(out + i) = o;
}

// ---------------- transpose + cast: in (R,C) f32 -> out (C,R) bf16 ----------------
__global__ __launch_bounds__(256) void transpose_cast_k(const float* __restrict__ in,
                                                        ushort* __restrict__ out, int R, int C) {
  __shared__ ushort tile[64][66];
  const int r0 = blockIdx.y * 64, c0 = blockIdx.x * 64;
  const int tid = threadIdx.x;
  #pragma unroll
  for (int j = 0; j < 16; ++j) {
    int idx = j * 256 + tid;
    int r = idx >> 6, c = idx & 63;
    tile[c][r] = f2bf(in[(size_t)(r0 + r) * C + c0 + c]);
  }
  __syncthreads();
  #pragma unroll
  for (int j = 0; j < 16; ++j) {
    int idx = j * 256 + tid;
    int c = idx >> 6, r = idx & 63;
    out[(size_t)(c0 + c) * R + r0 + r] = tile[c][r];
  }
}

// ---------------- RoPE tables ----------------
__global__ __launch_bounds__(256) void rope_table_k(float2* __restrict__ tab) {
  int idx = blockIdx.x * 256 + threadIdx.x;   // T*32 = 65536
  int t = idx >> 5, i = idx & 31;
  float inv = expf(-(float)i * 0.28782313662425575f);  // ln(10000)/32
  float ang = (float)t * inv;
  tab[idx] = make_float2(cosf(ang), sinf(ang));
}

// ---------------- fused QKV GEMM: 128x128 tile, 2-phase engine, round-0 epilogue ----------------
// grid (24,32) = 768 blocks = 3 exact passes on 256 CUs; 2 blocks/CU resident.
__global__ __launch_bounds__(256) void gemm_qkv_2ph(const ushort* __restrict__ A,
                                                    const ushort* __restrict__ BT,
                                                    const float2* __restrict__ tab,
                                                    ushort* __restrict__ Qp,
                                                    ushort* __restrict__ Kp,
                                                    ushort* __restrict__ Vp) {
  constexpr int K = 2048, NKT = 32;
  __shared__ __attribute__((aligned(128))) ushort smem[32768];   // 64 KiB
  ushort* Asm = smem;            // [2][128*64]
  ushort* Bsm = smem + 16384;    // [2][128*64]
  ushort* Ot = smem;             // epilogue tile [128][132] (33.8 KB, reuse)

  const int tid = threadIdx.x;
  const int ln = tid & 63, wv = tid >> 6;
  const int g = ln >> 4, l15 = ln & 15, l31 = ln & 31, hi = ln >> 5;
  const int wm = wv >> 1, wn = wv & 1;
  const int m0 = blockIdx.y * 128, n0 = blockIdx.x * 128;

  f32x4 acc[4][4];
  #pragma unroll
  for (int i = 0; i < 4; ++i)
    #pragma unroll
    for (int j = 0; j < 4; ++j) acc[i][j] = (f32x4){0.f, 0.f, 0.f, 0.f};

  kloop2(A, BT, Asm, Bsm, m0, n0, K, NKT, acc, tid, wm, wn, g, l15);

  // ---- epilogue: RoPE in-register, bf16 tile to LDS, packed chunk stores ----
  // (round-0 bit-verified code, unchanged)
  __syncthreads();                 // all waves done reading Asm/Bsm
  const int bq = m0 >> 11;         // batch (block-uniform)
  const int tg0 = m0 & 2047;       // first global t of this block
  const int type = (n0 < 2048) ? 0 : (n0 < 2560 ? 1 : 2);   // Q / K / V

  #pragma unroll
  for (int mi = 0; mi < 4; ++mi)
    #pragma unroll
    for (int r = 0; r < 4; ++r) {
      const int tl = wm * 64 + mi * 16 + g * 4 + r;       // local t row
      const int t = tg0 + tl;
      #pragma unroll
      for (int ni = 0; ni < 4; ++ni) {
        const int cl = wn * 64 + ni * 16 + l15;           // local col
        float val = acc[mi][ni][r];
        float outv;
        if (type < 2) {                                    // RoPE (Q and K)
          float pairv = acc[mi][ni ^ 2][r];
          float2 cs = tab[t * 32 + (ni & 1) * 16 + l15];
          outv = (ni & 2) ? (val * cs.x + pairv * cs.y) : (val * cs.x - pairv * cs.y);
          if (type == 0) outv *= 0.18033688011112042f;     // 0.125 * log2(e)
        } else {
          outv = val;
        }
        Ot[tl * 132 + cl] = f2bf(outv);
      }
    }
  __syncthreads();

  // 32 chunks: id = wv*8+it -> hl = id>>4 (head-local), q4 = (id>>2)&3, fi = id&3
  #pragma unroll
  for (int it = 0; it < 8; ++it) {
    const int id = wv * 8 + it;
    const int hl = id >> 4, q4 = (id >> 2) & 3, fi = id & 3;
    const int tile = (tg0 >> 5) + q4;
    if (type < 2) {
      const ushort* srow = Ot + (q4 * 32 + l31) * 132 + hl * 64 + fi * 16 + hi * 8;
      union { s16x4 h[2]; s16x8 v; } u;
      u.h[0] = *(const s16x4*)srow;
      u.h[1] = *(const s16x4*)(srow + 4);
      ushort* dst;
      if (type == 0) {
        const int h = (n0 >> 6) + hl;
        dst = Qp + (((size_t)(bq * 32 + h) * 64 + tile) * 4 + fi) * 512 + ln * 8;
      } else {
        const int h = ((n0 - 2048) >> 6) + hl;
        dst = Kp + (((size_t)(bq * 8 + h) * 64 + tile) * 4 + fi) * 512 + ln * 8;
      }
      *(s16x8*)dst = u.v;
    } else {
      const int hk = ((n0 - 2560) >> 6) + hl;
      const int col = hl * 64 + (fi & 1) * 32 + l31;
      const int row0 = q4 * 32 + (fi >> 1) * 16 + hi * 8;
      ushort o[8];
      #pragma unroll
      for (int j = 0; j < 8; ++j) o[j] = Ot[(row0 + j) * 132 + col];
      ushort* dst = Vp + (((size_t)(bq * 8 + hk) * 64 + tile) * 4 + fi) * 512 + ln * 8;
      *(s16x8*)dst = *(const s16x8*)o;
    }
  }
}

// ---------------- Wo GEMM: 128x128 tile, 2-phase engine, plain f32 store ----------------
// grid (16,32) = 512 blocks = 2 exact passes; 2 blocks/CU resident.
__global__ __launch_bounds__(256) void gemm_bt_2ph(const ushort* __restrict__ A,
                                                   const ushort* __restrict__ BT,
                                                   float* __restrict__ C, int M, int N, int K) {
  __shared__ __attribute__((aligned(128))) ushort smem[32768];   // 64 KiB
  ushort* Asm = smem;
  ushort* Bsm = smem + 16384;

  const int tid = threadIdx.x;
  const int ln = tid & 63, wv = tid >> 6;
  const int g = ln >> 4, l15 = ln & 15;
  const int wm = wv >> 1, wn = wv & 1;
  const int m0 = blockIdx.y * 128, n0 = blockIdx.x * 128;
  const int NKT = K / 64;

  f32x4 acc[4][4];
  #pragma unroll
  for (int i = 0; i < 4; ++i)
    #pragma unroll
    for (int j = 0; j < 4; ++j) acc[i][j] = (f32x4){0.f, 0.f, 0.f, 0.f};

  kloop2(A, BT, Asm, Bsm, m0, n0, K, NKT, acc, tid, wm, wn, g, l15);

  #pragma unroll
  for (int mi = 0; mi < 4; ++mi)
    #pragma unroll
    for (int r = 0; r < 4; ++r) {
      int row = m0 + wm * 64 + mi * 16 + g * 4 + r;
      float* crow = C + (size_t)row * N + n0 + wn * 64 + l15;
      #pragma unroll
      for (int ni = 0; ni < 4; ++ni) crow[ni * 16] = acc[mi][ni][r];
    }
}

// ---------------- causal GQA flash attention, swapped-QK^T 32x32, barrier-free ----------------
__global__ __launch_bounds__(256) void attn_k(const ushort* __restrict__ Qp,
                                              const ushort* __restrict__ Kp,
                                              const ushort* __restrict__ Vp,
                                              ushort* __restrict__ O) {
  __shared__ ushort ep[4][32 * 64];   // per-wave epilogue transpose patch
  const int tid = threadIdx.x, wv = tid >> 6, ln = tid & 63;
  const int l31 = ln & 31, hi = ln >> 5;

  const int f = blockIdx.x + gridDim.x * (blockIdx.y + 32 * blockIdx.z);  // 0..1023
  const int xcd = f & 7, j = f >> 3;         // j: 0..127
  const int pr = xcd + 8 * (j & 1);          // (b,hk) pair id, 0..15
  const int b = pr >> 3, hk = pr & 7;
  const int s = j >> 1;                      // 0..63
  const int hq = hk * 4 + (s & 3);
  const int qtile = 63 - ((s >> 2) * 4 + wv);   // LJF
  const int qw = qtile * 32;
  const int nt = qtile + 1;

  const ushort* Qh    = Qp + ((size_t)(b * 32 + hq)) * (64 * 2048);
  const ushort* Kbase = Kp + ((size_t)(b * 8 + hk)) * (64 * 2048);
  const ushort* Vbase = Vp + ((size_t)(b * 8 + hk)) * (64 * 2048);
  ushort* lds = ep[wv];

  s16x8 qf[4];
  {
    const ushort* qp_ = Qh + (size_t)qtile * 2048 + ln * 8;
    #pragma unroll
    for (int ks = 0; ks < 4; ++ks) qf[ks] = *(const s16x8*)(qp_ + ks * 512);
  }

  f32x16 oacc[2];
  #pragma unroll
  for (int dt = 0; dt < 2; ++dt)
    #pragma unroll
    for (int r = 0; r < 16; ++r) oacc[dt][r] = 0.f;
  float m = -1e30f, l = 0.f;

  const ushort* kp = Kbase + ln * 8;
  const ushort* vp = Vbase + ln * 8;

  s16x8 kf[4];
  #pragma unroll
  for (int ks = 0; ks < 4; ++ks) kf[ks] = *(const s16x8*)(kp + ks * 512);
  kp += 2048;

  s16x8 vc[4];
  union pfu { unsigned u[4]; s16x8 v; };
  pfu pf0, pf1;

  #pragma unroll 1
  for (int kt = 0; kt < nt; ++kt) {
    if (kt) {
      __builtin_amdgcn_s_setprio(1);
      oacc[0] = __builtin_amdgcn_mfma_f32_32x32x16_bf16(vc[0], pf0.v, oacc[0], 0, 0, 0);
      oacc[1] = __builtin_amdgcn_mfma_f32_32x32x16_bf16(vc[1], pf0.v, oacc[1], 0, 0, 0);
      oacc[0] = __builtin_amdgcn_mfma_f32_32x32x16_bf16(vc[2], pf1.v, oacc[0], 0, 0, 0);
      oacc[1] = __builtin_amdgcn_mfma_f32_32x32x16_bf16(vc[3], pf1.v, oacc[1], 0, 0, 0);
      __builtin_amdgcn_s_setprio(0);
    }
    #pragma unroll
    for (int fi2 = 0; fi2 < 4; ++fi2) vc[fi2] = *(const s16x8*)(vp + fi2 * 512);
    vp += 2048;

    f32x16 sp;
    #pragma unroll
    for (int r = 0; r < 16; ++r) sp[r] = 0.f;
    __builtin_amdgcn_s_setprio(1);
    #pragma unroll
    for (int ks = 0; ks < 4; ++ks)
      sp = __builtin_amdgcn_mfma_f32_32x32x16_bf16(kf[ks], qf[ks], sp, 0, 0, 0);
    __builtin_amdgcn_s_setprio(0);

    if (kt + 1 < nt) {
      #pragma unroll
      for (int ks = 0; ks < 4; ++ks) kf[ks] = *(const s16x8*)(kp + ks * 512);
      kp += 2048;
    }

    if (kt == qtile) {
      #pragma unroll
      for (int r = 0; r < 16; ++r) {
        int key = (r & 3) + 8 * (r >> 2) + 4 * hi;
        if (key > l31) sp[r] = -1e30f;
      }
    }

    float t0 = fmaxf(fmaxf(sp[0], sp[1]), sp[2]);
    float t1 = fmaxf(fmaxf(sp[3], sp[4]), sp[5]);
    float t2 = fmaxf(fmaxf(sp[6], sp[7]), sp[8]);
    float t3 = fmaxf(fmaxf(sp[9], sp[10]), sp[11]);
    float t4 = fmaxf(fmaxf(sp[12], sp[13]), sp[14]);
    float u0 = fmaxf(fmaxf(t0, t1), t2);
    float u1 = fmaxf(fmaxf(t3, t4), sp[15]);
    float pm = fmaxf(u0, u1);
    pm = fmaxf(pm, __shfl_xor(pm, 32, 64));

    if (__any(pm > m)) {
      float mn = fmaxf(m, pm);
      float alpha = __builtin_amdgcn_exp2f(m - mn);
      m = mn;
      l *= alpha;
      #pragma unroll
      for (int dt = 0; dt < 2; ++dt)
        #pragma unroll
        for (int r = 0; r < 16; ++r) oacc[dt][r] *= alpha;
    }

    #pragma unroll
    for (int r = 0; r < 16; ++r) sp[r] = __builtin_amdgcn_exp2f(sp[r] - m);
    {
      float a0 = sp[0] + sp[1], a1 = sp[2] + sp[3], a2 = sp[4] + sp[5], a3 = sp[6] + sp[7];
      float a4 = sp[8] + sp[9], a5 = sp[10] + sp[11], a6 = sp[12] + sp[13], a7 = sp[14] + sp[15];
      float b0 = a0 + a1, b1 = a2 + a3, b2 = a4 + a5, b3 = a6 + a7;
      float rs = (b0 + b1) + (b2 + b3);
      rs += __shfl_xor(rs, 32, 64);
      l += rs;
    }

    unsigned cw[8], xs[8];
    #pragma unroll
    for (int jj = 0; jj < 8; ++jj) {
      union { __hip_bfloat162 h; unsigned u; } pk;
      pk.h = __float22bfloat162_rn(make_float2(sp[2 * jj], sp[2 * jj + 1]));
      cw[jj] = pk.u;
    }
    #pragma unroll
    for (int jj = 0; jj < 8; ++jj) xs[jj] = __shfl_xor(cw[jj], 32, 64);
    pf0.u[0] = hi ? xs[2] : cw[0];
    pf0.u[1] = hi ? xs[3] : cw[1];
    pf0.u[2] = hi ? cw[2] : xs[0];
    pf0.u[3] = hi ? cw[3] : xs[1];
    pf1.u[0] = hi ? xs[6] : cw[4];
    pf1.u[1] = hi ? xs[7] : cw[5];
    pf1.u[2] = hi ? cw[6] : xs[4];
    pf1.u[3] = hi ? cw[7] : xs[5];
  }

  __builtin_amdgcn_s_setprio(1);
  oacc[0] = __builtin_amdgcn_mfma_f32_32x32x16_bf16(vc[0], pf0.v, oacc[0], 0, 0, 0);
  oacc[1] = __builtin_amdgcn_mfma_f32_32x32x16_bf16(vc[1], pf0.v, oacc[1], 0, 0, 0);
  oacc[0] = __builtin_amdgcn_mfma_f32_32x32x16_bf16(vc[2], pf1.v, oacc[0], 0, 0, 0);
  oacc[1] = __builtin_amdgcn_mfma_f32_32x32x16_bf16(vc[3], pf1.v, oacc[1], 0, 0, 0);
  __builtin_amdgcn_s_setprio(0);

  float invl = 1.0f / l;
  #pragma unroll
  for (int dt = 0; dt < 2; ++dt)
    #pragma unroll
    for (int r = 0; r < 16; ++r) {
      int d = dt * 32 + (r & 3) + 8 * (r >> 2) + 4 * hi;
      int byte = (l31 * 128 + d * 2) ^ ((l31 & 7) << 4);
      *(ushort*)((char*)lds + byte) = f2bf(oacc[dt][r] * invl);
    }
  const int qr = ln >> 1, half = ln & 1;
  #pragma unroll
  for (int jj = 0; jj < 4; ++jj) {
    int byte = (qr * 128 + half * 64 + jj * 16) ^ ((qr & 7) << 4);
    s16x8 vrow = *(const s16x8*)((const char*)lds + byte);
    *(s16x8*)(O + ((size_t)(b * 2048 + qw + qr)) * 2048 + hq * 64 + half * 32 + jj * 8) = vrow;
  }
}

extern "C" void kernel_launch(void* const* d_in, const int* in_sizes, int n_in,
                              void* d_out, int out_size, void* d_ws, size_t ws_size,
                              hipStream_t stream) {
  const float* x   = (const float*)d_in[0];
  const float* Wq  = (const float*)d_in[1];
  const float* Wkv = (const float*)d_in[2];
  const float* Wo  = (const float*)d_in[3];
  float* out = (float*)d_out;

  char* ws = (char*)d_ws;
  ushort* xb     = (ushort*)(ws);                 // 16 MiB  x bf16 (4096x2048)
  ushort* WqkvT  = (ushort*)(ws + 16777216);      // 12 MiB  [Wq|Wkv]^T bf16 (3072x2048)
  ushort* WoT    = (ushort*)(ws + 29360128);      //  8 MiB  Wo^T bf16 (2048x2048)
  float2* tab    = (float2*)(ws + 37748736);      // 512 KiB rope tables
  ushort* Qp     = (ushort*)(ws + 38273024);      // 16 MiB  Q packed
  ushort* Kp     = (ushort*)(ws + 55050240);      //  4 MiB  K packed
  ushort* Vp     = (ushort*)(ws + 59244544);      //  4 MiB  V packed
  ushort* Ob     = (ushort*)(ws + 63438848);      // 16 MiB  attn out bf16 (4096x2048)

  cast_bf16_k<<<8192, 256, 0, stream>>>(x, xb, 2 * 2048 * 2048);
  transpose_cast_k<<<dim3(32, 32), 256, 0, stream>>>(Wq, WqkvT, 2048, 2048);
  transpose_cast_k<<<dim3(16, 32), 256, 0, stream>>>(Wkv, WqkvT + 2048 * 2048, 2048, 1024);
  transpose_cast_k<<<dim3(32, 32), 256, 0, stream>>>(Wo, WoT, 2048, 2048);
  rope_table_k<<<256, 256, 0, stream>>>(tab);
  gemm_qkv_2ph<<<dim3(24, 32), 256, 0, stream>>>(xb, WqkvT, tab, Qp, Kp, Vp);
  attn_k<<<dim3(16, 32, 2), 256, 0, stream>>>(Qp, Kp, Vp, Ob);
  gemm_bt_2ph<<<dim3(16, 32), 256, 0, stream>>>(Ob, WoT, out, 4096, 2048, 2048);
}

// Round 9
// 220.055 us; speedup vs baseline: 1.4417x; 1.0544x over previous
//
#include <hip/hip_runtime.h>
#include <hip/hip_bf16.h>

#define DEVI __device__ __forceinline__

typedef __attribute__((ext_vector_type(4))) float f32x4;
typedef __attribute__((ext_vector_type(16))) float f32x16;
typedef __attribute__((ext_vector_type(8))) short s16x8;
typedef __attribute__((ext_vector_type(4))) short s16x4;

DEVI ushort f2bf(float f) {
  union { float f; unsigned u; } v; v.f = f;
  unsigned r = v.u + 0x7FFFu + ((v.u >> 16) & 1u);
  return (ushort)(r >> 16);
}

DEVI void gload_lds16(const void* g, void* l) {
  __builtin_amdgcn_global_load_lds((const __attribute__((address_space(1))) void*)g,
                                   (__attribute__((address_space(3))) void*)l, 16, 0, 0);
}

#define MFMA16 __builtin_amdgcn_mfma_f32_16x16x32_bf16
#define SBAR() __builtin_amdgcn_s_barrier()
#define LGKM0() asm volatile("s_waitcnt lgkmcnt(0)")

// Stage one 128x64 bf16 tile (1024 x 16B chunks) with 256 threads: 4 chunks each.
// Pre-swizzled global source + linear LDS dest (rule #21 pairing with ldfrag).
DEVI void stage128q(const ushort* __restrict__ gsrc, int K, ushort* ld, int tid) {
  #pragma unroll
  for (int j = 0; j < 4; ++j) {
    const int ci = j * 256 + tid;
    const int row = ci >> 3, c = ci & 7;
    gload_lds16(gsrc + (size_t)row * K + ((c ^ (row & 7)) << 3),
                ld + (size_t)(j * 256 + (tid & ~63)) * 8);
  }
}

DEVI s16x8 ldfrag(const ushort* tile, int row, int kc) {
  return *(const s16x8*)((const char*)tile + row * 128 + ((kc ^ (row & 7)) << 4));
}

// =====================================================================
// Single-barrier triple-B K-loop.  BM=BN=128, BK=64, 256 thr / 4 waves (2x2),
// wave tile 64x64 (no-spill register class: acc 64 AGPR + frags 64 VGPR).
// LDS 80 KiB (A 2x16K dbuf + B 3x16K tbuf) -> 2 blocks/CU (160 KiB exactly).
//
// Round-8's engine paid 3 s_barrier + lgkm + vmcnt per K-tile; barriers #2/#3
// only protected staging B(t+2) into the LIVE buffer (2-buf B).  With B
// triple-buffered, B(t+2) -> buf[(t+2)%3] is never the live buffer, and every
// stage target's last reader drained (own lgkmcnt(0)) before the previous
// iteration's closing barrier.  So ONE barrier per K-tile suffices:
//   { 16 ds_read frags; stage A(t+1)->alt, B(t+2)->buf[(t+2)%3];
//     lgkm0 + sched_barrier; prio1; 32 MFMA; prio0; vmcnt(4); SBAR }
// vmcnt(4): outstanding = B(t+1)[4, from t-1] + A(t+1)[4] + B(t+2)[4] = 12;
// drain 8 oldest -> A(t+1)/B(t+1) landed for next iter, B(t+2) stays in
// flight across the barrier (T4 counted-vmcnt).  Cross-wave completion of a
// tile staged at t-2: drained by each wave's vmcnt(4) at t-1 + barrier.
// =====================================================================
DEVI void kloop3(const ushort* __restrict__ A, const ushort* __restrict__ BT,
                 ushort* Asm, ushort* Bsm, int m0, int n0, int K, int NKT,
                 f32x4 (&acc)[4][4], int tid, int wm, int wn, int g, int l15) {
  // prologue: A(0)->A0, B(0)->B0, B(1)->B1; A0/B0 must land, B1 may fly
  stage128q(A + (size_t)m0 * K, K, Asm, tid);
  stage128q(BT + (size_t)n0 * K, K, Bsm, tid);
  stage128q(BT + (size_t)n0 * K + 64, K, Bsm + 8192, tid);
  asm volatile("s_waitcnt vmcnt(4)");
  SBAR();

  int rd = 0;                       // B read-buffer index = t % 3
  #pragma unroll 1
  for (int t = 0; t < NKT; ++t) {
    const ushort* Ah = Asm + (t & 1) * 8192;
    const ushort* Bh = Bsm + rd * 8192;
    s16x8 af[4][2], bfr[4][2];

    #pragma unroll
    for (int ks = 0; ks < 2; ++ks) {
      #pragma unroll
      for (int ni = 0; ni < 4; ++ni)
        bfr[ni][ks] = ldfrag(Bh, wn * 64 + ni * 16 + l15, ks * 4 + g);
      #pragma unroll
      for (int mi = 0; mi < 4; ++mi)
        af[mi][ks] = ldfrag(Ah, wm * 64 + mi * 16 + l15, ks * 4 + g);
    }
    if (t + 1 < NKT)
      stage128q(A + (size_t)m0 * K + (t + 1) * 64, K, Asm + ((t + 1) & 1) * 8192, tid);
    int wr = rd + 2; if (wr >= 3) wr -= 3;           // (t+2) % 3
    if (t + 2 < NKT)
      stage128q(BT + (size_t)n0 * K + (t + 2) * 64, K, Bsm + wr * 8192, tid);

    LGKM0();
    __builtin_amdgcn_sched_barrier(0);
    __builtin_amdgcn_s_setprio(1);
    #pragma unroll
    for (int mi = 0; mi < 4; ++mi)
      #pragma unroll
      for (int ni = 0; ni < 2; ++ni)
        #pragma unroll
        for (int ks = 0; ks < 2; ++ks)
          acc[mi][ni] = MFMA16(af[mi][ks], bfr[ni][ks], acc[mi][ni], 0, 0, 0);
    #pragma unroll
    for (int mi = 0; mi < 4; ++mi)
      #pragma unroll
      for (int ni = 0; ni < 2; ++ni)
        #pragma unroll
        for (int ks = 0; ks < 2; ++ks)
          acc[mi][2 + ni] = MFMA16(af[mi][ks], bfr[2 + ni][ks], acc[mi][2 + ni], 0, 0, 0);
    __builtin_amdgcn_s_setprio(0);

    if (t + 2 < NKT)      asm volatile("s_waitcnt vmcnt(4)");
    else if (t + 1 < NKT) asm volatile("s_waitcnt vmcnt(0)");
    SBAR();
    rd = (rd == 2) ? 0 : rd + 1;
  }
}

// ---------------- elementwise cast ----------------
__global__ __launch_bounds__(256) void cast_bf16_k(const float* __restrict__ in,
                                                   ushort* __restrict__ out, int n) {
  int i = (blockIdx.x * 256 + threadIdx.x) * 4;
  if (i >= n) return;
  float4 v = *(const float4*)(in + i);
  ushort4 o;
  o.x = f2bf(v.x); o.y = f2bf(v.y); o.z = f2bf(v.z); o.w = f2bf(v.w);
  *(ushort4*)(out + i) = o;
}

// ---------------- transpose + cast: in (R,C) f32 -> out (C,R) bf16 ----------------
__global__ __launch_bounds__(256) void transpose_cast_k(const float* __restrict__ in,
                                                        ushort* __restrict__ out, int R, int C) {
  __shared__ ushort tile[64][66];
  const int r0 = blockIdx.y * 64, c0 = blockIdx.x * 64;
  const int tid = threadIdx.x;
  #pragma unroll
  for (int j = 0; j < 16; ++j) {
    int idx = j * 256 + tid;
    int r = idx >> 6, c = idx & 63;
    tile[c][r] = f2bf(in[(size_t)(r0 + r) * C + c0 + c]);
  }
  __syncthreads();
  #pragma unroll
  for (int j = 0; j < 16; ++j) {
    int idx = j * 256 + tid;
    int c = idx >> 6, r = idx & 63;
    out[(size_t)(c0 + c) * R + r0 + r] = tile[c][r];
  }
}

// ---------------- RoPE tables ----------------
__global__ __launch_bounds__(256) void rope_table_k(float2* __restrict__ tab) {
  int idx = blockIdx.x * 256 + threadIdx.x;   // T*32 = 65536
  int t = idx >> 5, i = idx & 31;
  float inv = expf(-(float)i * 0.28782313662425575f);  // ln(10000)/32
  float ang = (float)t * inv;
  tab[idx] = make_float2(cosf(ang), sinf(ang));
}

// ---------------- fused QKV GEMM: 128x128 tile, single-barrier engine ----------------
// grid (24,32) = 768 blocks; 2 blocks/CU resident (80 KiB LDS).
__global__ __launch_bounds__(256) void gemm_qkv_3b(const ushort* __restrict__ A,
                                                   const ushort* __restrict__ BT,
                                                   const float2* __restrict__ tab,
                                                   ushort* __restrict__ Qp,
                                                   ushort* __restrict__ Kp,
                                                   ushort* __restrict__ Vp) {
  constexpr int K = 2048, NKT = 32;
  __shared__ __attribute__((aligned(128))) ushort smem[40960];   // 80 KiB
  ushort* Asm = smem;            // [2][128*64]
  ushort* Bsm = smem + 16384;    // [3][128*64]
  ushort* Ot = smem;             // epilogue tile [128][132] (33.8 KB, reuse)

  const int tid = threadIdx.x;
  const int ln = tid & 63, wv = tid >> 6;
  const int g = ln >> 4, l15 = ln & 15, l31 = ln & 31, hi = ln >> 5;
  const int wm = wv >> 1, wn = wv & 1;
  const int m0 = blockIdx.y * 128, n0 = blockIdx.x * 128;

  f32x4 acc[4][4];
  #pragma unroll
  for (int i = 0; i < 4; ++i)
    #pragma unroll
    for (int j = 0; j < 4; ++j) acc[i][j] = (f32x4){0.f, 0.f, 0.f, 0.f};

  kloop3(A, BT, Asm, Bsm, m0, n0, K, NKT, acc, tid, wm, wn, g, l15);

  // ---- epilogue: RoPE in-register, bf16 tile to LDS, packed chunk stores ----
  // (round-0 bit-verified code, unchanged)
  __syncthreads();                 // all waves done reading Asm/Bsm
  const int bq = m0 >> 11;         // batch (block-uniform)
  const int tg0 = m0 & 2047;       // first global t of this block
  const int type = (n0 < 2048) ? 0 : (n0 < 2560 ? 1 : 2);   // Q / K / V

  #pragma unroll
  for (int mi = 0; mi < 4; ++mi)
    #pragma unroll
    for (int r = 0; r < 4; ++r) {
      const int tl = wm * 64 + mi * 16 + g * 4 + r;       // local t row
      const int t = tg0 + tl;
      #pragma unroll
      for (int ni = 0; ni < 4; ++ni) {
        const int cl = wn * 64 + ni * 16 + l15;           // local col
        float val = acc[mi][ni][r];
        float outv;
        if (type < 2) {                                    // RoPE (Q and K)
          float pairv = acc[mi][ni ^ 2][r];
          float2 cs = tab[t * 32 + (ni & 1) * 16 + l15];
          outv = (ni & 2) ? (val * cs.x + pairv * cs.y) : (val * cs.x - pairv * cs.y);
          if (type == 0) outv *= 0.18033688011112042f;     // 0.125 * log2(e)
        } else {
          outv = val;
        }
        Ot[tl * 132 + cl] = f2bf(outv);
      }
    }
  __syncthreads();

  // 32 chunks: id = wv*8+it -> hl = id>>4 (head-local), q4 = (id>>2)&3, fi = id&3
  #pragma unroll
  for (int it = 0; it < 8; ++it) {
    const int id = wv * 8 + it;
    const int hl = id >> 4, q4 = (id >> 2) & 3, fi = id & 3;
    const int tile = (tg0 >> 5) + q4;
    if (type < 2) {
      const ushort* srow = Ot + (q4 * 32 + l31) * 132 + hl * 64 + fi * 16 + hi * 8;
      union { s16x4 h[2]; s16x8 v; } u;
      u.h[0] = *(const s16x4*)srow;
      u.h[1] = *(const s16x4*)(srow + 4);
      ushort* dst;
      if (type == 0) {
        const int h = (n0 >> 6) + hl;
        dst = Qp + (((size_t)(bq * 32 + h) * 64 + tile) * 4 + fi) * 512 + ln * 8;
      } else {
        const int h = ((n0 - 2048) >> 6) + hl;
        dst = Kp + (((size_t)(bq * 8 + h) * 64 + tile) * 4 + fi) * 512 + ln * 8;
      }
      *(s16x8*)dst = u.v;
    } else {
      const int hk = ((n0 - 2560) >> 6) + hl;
      const int col = hl * 64 + (fi & 1) * 32 + l31;
      const int row0 = q4 * 32 + (fi >> 1) * 16 + hi * 8;
      ushort o[8];
      #pragma unroll
      for (int j = 0; j < 8; ++j) o[j] = Ot[(row0 + j) * 132 + col];
      ushort* dst = Vp + (((size_t)(bq * 8 + hk) * 64 + tile) * 4 + fi) * 512 + ln * 8;
      *(s16x8*)dst = *(const s16x8*)o;
    }
  }
}

// ---------------- Wo GEMM: 128x128 tile, single-barrier engine, f32 store ----------------
// grid (16,32) = 512 blocks; 2 blocks/CU resident.
__global__ __launch_bounds__(256) void gemm_bt_3b(const ushort* __restrict__ A,
                                                  const ushort* __restrict__ BT,
                                                  float* __restrict__ C, int M, int N, int K) {
  __shared__ __attribute__((aligned(128))) ushort smem[40960];   // 80 KiB
  ushort* Asm = smem;
  ushort* Bsm = smem + 16384;

  const int tid = threadIdx.x;
  const int ln = tid & 63, wv = tid >> 6;
  const int g = ln >> 4, l15 = ln & 15;
  const int wm = wv >> 1, wn = wv & 1;
  const int m0 = blockIdx.y * 128, n0 = blockIdx.x * 128;
  const int NKT = K / 64;

  f32x4 acc[4][4];
  #pragma unroll
  for (int i = 0; i < 4; ++i)
    #pragma unroll
    for (int j = 0; j < 4; ++j) acc[i][j] = (f32x4){0.f, 0.f, 0.f, 0.f};

  kloop3(A, BT, Asm, Bsm, m0, n0, K, NKT, acc, tid, wm, wn, g, l15);

  #pragma unroll
  for (int mi = 0; mi < 4; ++mi)
    #pragma unroll
    for (int r = 0; r < 4; ++r) {
      int row = m0 + wm * 64 + mi * 16 + g * 4 + r;
      float* crow = C + (size_t)row * N + n0 + wn * 64 + l15;
      #pragma unroll
      for (int ni = 0; ni < 4; ++ni) crow[ni * 16] = acc[mi][ni][r];
    }
}

// ---------------- causal GQA flash attention, swapped-QK^T 32x32, barrier-free ----------------
__global__ __launch_bounds__(256) void attn_k(const ushort* __restrict__ Qp,
                                              const ushort* __restrict__ Kp,
                                              const ushort* __restrict__ Vp,
                                              ushort* __restrict__ O) {
  __shared__ ushort ep[4][32 * 64];   // per-wave epilogue transpose patch
  const int tid = threadIdx.x, wv = tid >> 6, ln = tid & 63;
  const int l31 = ln & 31, hi = ln >> 5;

  const int f = blockIdx.x + gridDim.x * (blockIdx.y + 32 * blockIdx.z);  // 0..1023
  const int xcd = f & 7, j = f >> 3;         // j: 0..127
  const int pr = xcd + 8 * (j & 1);          // (b,hk) pair id, 0..15
  const int b = pr >> 3, hk = pr & 7;
  const int s = j >> 1;                      // 0..63
  const int hq = hk * 4 + (s & 3);
  const int qtile = 63 - ((s >> 2) * 4 + wv);   // LJF
  const int qw = qtile * 32;
  const int nt = qtile + 1;

  const ushort* Qh    = Qp + ((size_t)(b * 32 + hq)) * (64 * 2048);
  const ushort* Kbase = Kp + ((size_t)(b * 8 + hk)) * (64 * 2048);
  const ushort* Vbase = Vp + ((size_t)(b * 8 + hk)) * (64 * 2048);
  ushort* lds = ep[wv];

  s16x8 qf[4];
  {
    const ushort* qp_ = Qh + (size_t)qtile * 2048 + ln * 8;
    #pragma unroll
    for (int ks = 0; ks < 4; ++ks) qf[ks] = *(const s16x8*)(qp_ + ks * 512);
  }

  f32x16 oacc[2];
  #pragma unroll
  for (int dt = 0; dt < 2; ++dt)
    #pragma unroll
    for (int r = 0; r < 16; ++r) oacc[dt][r] = 0.f;
  float m = -1e30f, l = 0.f;

  const ushort* kp = Kbase + ln * 8;
  const ushort* vp = Vbase + ln * 8;

  s16x8 kf[4];
  #pragma unroll
  for (int ks = 0; ks < 4; ++ks) kf[ks] = *(const s16x8*)(kp + ks * 512);
  kp += 2048;

  s16x8 vc[4];
  union pfu { unsigned u[4]; s16x8 v; };
  pfu pf0, pf1;

  #pragma unroll 1
  for (int kt = 0; kt < nt; ++kt) {
    if (kt) {
      __builtin_amdgcn_s_setprio(1);
      oacc[0] = __builtin_amdgcn_mfma_f32_32x32x16_bf16(vc[0], pf0.v, oacc[0], 0, 0, 0);
      oacc[1] = __builtin_amdgcn_mfma_f32_32x32x16_bf16(vc[1], pf0.v, oacc[1], 0, 0, 0);
      oacc[0] = __builtin_amdgcn_mfma_f32_32x32x16_bf16(vc[2], pf1.v, oacc[0], 0, 0, 0);
      oacc[1] = __builtin_amdgcn_mfma_f32_32x32x16_bf16(vc[3], pf1.v, oacc[1], 0, 0, 0);
      __builtin_amdgcn_s_setprio(0);
    }
    #pragma unroll
    for (int fi2 = 0; fi2 < 4; ++fi2) vc[fi2] = *(const s16x8*)(vp + fi2 * 512);
    vp += 2048;

    f32x16 sp;
    #pragma unroll
    for (int r = 0; r < 16; ++r) sp[r] = 0.f;
    __builtin_amdgcn_s_setprio(1);
    #pragma unroll
    for (int ks = 0; ks < 4; ++ks)
      sp = __builtin_amdgcn_mfma_f32_32x32x16_bf16(kf[ks], qf[ks], sp, 0, 0, 0);
    __builtin_amdgcn_s_setprio(0);

    if (kt + 1 < nt) {
      #pragma unroll
      for (int ks = 0; ks < 4; ++ks) kf[ks] = *(const s16x8*)(kp + ks * 512);
      kp += 2048;
    }

    if (kt == qtile) {
      #pragma unroll
      for (int r = 0; r < 16; ++r) {
        int key = (r & 3) + 8 * (r >> 2) + 4 * hi;
        if (key > l31) sp[r] = -1e30f;
      }
    }

    float t0 = fmaxf(fmaxf(sp[0], sp[1]), sp[2]);
    float t1 = fmaxf(fmaxf(sp[3], sp[4]), sp[5]);
    float t2 = fmaxf(fmaxf(sp[6], sp[7]), sp[8]);
    float t3 = fmaxf(fmaxf(sp[9], sp[10]), sp[11]);
    float t4 = fmaxf(fmaxf(sp[12], sp[13]), sp[14]);
    float u0 = fmaxf(fmaxf(t0, t1), t2);
    float u1 = fmaxf(fmaxf(t3, t4), sp[15]);
    float pm = fmaxf(u0, u1);
    pm = fmaxf(pm, __shfl_xor(pm, 32, 64));

    if (__any(pm > m)) {
      float mn = fmaxf(m, pm);
      float alpha = __builtin_amdgcn_exp2f(m - mn);
      m = mn;
      l *= alpha;
      #pragma unroll
      for (int dt = 0; dt < 2; ++dt)
        #pragma unroll
        for (int r = 0; r < 16; ++r) oacc[dt][r] *= alpha;
    }

    #pragma unroll
    for (int r = 0; r < 16; ++r) sp[r] = __builtin_amdgcn_exp2f(sp[r] - m);
    {
      float a0 = sp[0] + sp[1], a1 = sp[2] + sp[3], a2 = sp[4] + sp[5], a3 = sp[6] + sp[7];
      float a4 = sp[8] + sp[9], a5 = sp[10] + sp[11], a6 = sp[12] + sp[13], a7 = sp[14] + sp[15];
      float b0 = a0 + a1, b1 = a2 + a3, b2 = a4 + a5, b3 = a6 + a7;
      float rs = (b0 + b1) + (b2 + b3);
      rs += __shfl_xor(rs, 32, 64);
      l += rs;
    }

    unsigned cw[8], xs[8];
    #pragma unroll
    for (int jj = 0; jj < 8; ++jj) {
      union { __hip_bfloat162 h; unsigned u; } pk;
      pk.h = __float22bfloat162_rn(make_float2(sp[2 * jj], sp[2 * jj + 1]));
      cw[jj] = pk.u;
    }
    #pragma unroll
    for (int jj = 0; jj < 8; ++jj) xs[jj] = __shfl_xor(cw[jj], 32, 64);
    pf0.u[0] = hi ? xs[2] : cw[0];
    pf0.u[1] = hi ? xs[3] : cw[1];
    pf0.u[2] = hi ? cw[2] : xs[0];
    pf0.u[3] = hi ? cw[3] : xs[1];
    pf1.u[0] = hi ? xs[6] : cw[4];
    pf1.u[1] = hi ? xs[7] : cw[5];
    pf1.u[2] = hi ? cw[6] : xs[4];
    pf1.u[3] = hi ? cw[7] : xs[5];
  }

  __builtin_amdgcn_s_setprio(1);
  oacc[0] = __builtin_amdgcn_mfma_f32_32x32x16_bf16(vc[0], pf0.v, oacc[0], 0, 0, 0);
  oacc[1] = __builtin_amdgcn_mfma_f32_32x32x16_bf16(vc[1], pf0.v, oacc[1], 0, 0, 0);
  oacc[0] = __builtin_amdgcn_mfma_f32_32x32x16_bf16(vc[2], pf1.v, oacc[0], 0, 0, 0);
  oacc[1] = __builtin_amdgcn_mfma_f32_32x32x16_bf16(vc[3], pf1.v, oacc[1], 0, 0, 0);
  __builtin_amdgcn_s_setprio(0);

  float invl = 1.0f / l;
  #pragma unroll
  for (int dt = 0; dt < 2; ++dt)
    #pragma unroll
    for (int r = 0; r < 16; ++r) {
      int d = dt * 32 + (r & 3) + 8 * (r >> 2) + 4 * hi;
      int byte = (l31 * 128 + d * 2) ^ ((l31 & 7) << 4);
      *(ushort*)((char*)lds + byte) = f2bf(oacc[dt][r] * invl);
    }
  const int qr = ln >> 1, half = ln & 1;
  #pragma unroll
  for (int jj = 0; jj < 4; ++jj) {
    int byte = (qr * 128 + half * 64 + jj * 16) ^ ((qr & 7) << 4);
    s16x8 vrow = *(const s16x8*)((const char*)lds + byte);
    *(s16x8*)(O + ((size_t)(b * 2048 + qw + qr)) * 2048 + hq * 64 + half * 32 + jj * 8) = vrow;
  }
}

extern "C" void kernel_launch(void* const* d_in, const int* in_sizes, int n_in,
                              void* d_out, int out_size, void* d_ws, size_t ws_size,
                              hipStream_t stream) {
  const float* x   = (const float*)d_in[0];
  const float* Wq  = (const float*)d_in[1];
  const float* Wkv = (const float*)d_in[2];
  const float* Wo  = (const float*)d_in[3];
  float* out = (float*)d_out;

  char* ws = (char*)d_ws;
  ushort* xb     = (ushort*)(ws);                 // 16 MiB  x bf16 (4096x2048)
  ushort* WqkvT  = (ushort*)(ws + 16777216);      // 12 MiB  [Wq|Wkv]^T bf16 (3072x2048)
  ushort* WoT    = (ushort*)(ws + 29360128);      //  8 MiB  Wo^T bf16 (2048x2048)
  float2* tab    = (float2*)(ws + 37748736);      // 512 KiB rope tables
  ushort* Qp     = (ushort*)(ws + 38273024);      // 16 MiB  Q packed
  ushort* Kp     = (ushort*)(ws + 55050240);      //  4 MiB  K packed
  ushort* Vp     = (ushort*)(ws + 59244544);      //  4 MiB  V packed
  ushort* Ob     = (ushort*)(ws + 63438848);      // 16 MiB  attn out bf16 (4096x2048)

  cast_bf16_k<<<8192, 256, 0, stream>>>(x, xb, 2 * 2048 * 2048);
  transpose_cast_k<<<dim3(32, 32), 256, 0, stream>>>(Wq, WqkvT, 2048, 2048);
  transpose_cast_k<<<dim3(16, 32), 256, 0, stream>>>(Wkv, WqkvT + 2048 * 2048, 2048, 1024);
  transpose_cast_k<<<dim3(32, 32), 256, 0, stream>>>(Wo, WoT, 2048, 2048);
  rope_table_k<<<256, 256, 0, stream>>>(tab);
  gemm_qkv_3b<<<dim3(24, 32), 256, 0, stream>>>(xb, WqkvT, tab, Qp, Kp, Vp);
  attn_k<<<dim3(16, 32, 2), 256, 0, stream>>>(Qp, Kp, Vp, Ob);
  gemm_bt_3b<<<dim3(16, 32), 256, 0, stream>>>(Ob, WoT, out, 4096, 2048, 2048);
}

// Round 11
// 210.679 us; speedup vs baseline: 1.5058x; 1.0445x over previous
//
#include <hip/hip_runtime.h>
#include <hip/hip_bf16.h>

#define DEVI __device__ __forceinline__

typedef __attribute__((ext_vector_type(4))) float f32x4;
typedef __attribute__((ext_vector_type(16))) float f32x16;
typedef __attribute__((ext_vector_type(8))) short s16x8;
typedef __attribute__((ext_vector_type(4))) short s16x4;
typedef __attribute__((ext_vector_type(2))) unsigned u32x2;

DEVI ushort f2bf(float f) {
  union { float f; unsigned u; } v; v.f = f;
  unsigned r = v.u + 0x7FFFu + ((v.u >> 16) & 1u);
  return (ushort)(r >> 16);
}

DEVI void gload_lds16(const void* g, void* l) {
  __builtin_amdgcn_global_load_lds((const __attribute__((address_space(1))) void*)g,
                                   (__attribute__((address_space(3))) void*)l, 16, 0, 0);
}

#define MFMA16 __builtin_amdgcn_mfma_f32_16x16x32_bf16
#define SBAR() __builtin_amdgcn_s_barrier()
#define LGKM0() asm volatile("s_waitcnt lgkmcnt(0)")

// Cross-half (lane i <-> lane i+32) exchange via the permlane32_swap BUILTIN.
// Round-10 bug: inline-asm "+v","+v" with two copies of the SAME value let the
// allocator coalesce both operands into one register -> self-swap -> corrupted
// row-max -> exp2 overflow -> NaN.  The builtin returns both results as fresh
// SSA values, so the dataflow is modeled and coalescing is impossible.
DEVI float plswap_max(float x) {
  union { float f; unsigned u; } a; a.f = x;
  u32x2 r = __builtin_amdgcn_permlane32_swap(a.u, a.u, false, false);
  union { unsigned u; float f; } o0, o1; o0.u = r[0]; o1.u = r[1];
  return fmaxf(o0.f, o1.f);
}
DEVI float plswap_sum(float x) {
  union { float f; unsigned u; } a; a.f = x;
  u32x2 r = __builtin_amdgcn_permlane32_swap(a.u, a.u, false, false);
  union { unsigned u; float f; } o0, o1; o0.u = r[0]; o1.u = r[1];
  return o0.f + o1.f;
}

// Stage one 128x64 bf16 tile (1024 x 16B chunks) with 256 threads: 4 chunks each.
// Pre-swizzled global source + linear LDS dest (rule #21 pairing with ldfrag).
DEVI void stage128q(const ushort* __restrict__ gsrc, int K, ushort* ld, int tid) {
  #pragma unroll
  for (int j = 0; j < 4; ++j) {
    const int ci = j * 256 + tid;
    const int row = ci >> 3, c = ci & 7;
    gload_lds16(gsrc + (size_t)row * K + ((c ^ (row & 7)) << 3),
                ld + (size_t)(j * 256 + (tid & ~63)) * 8);
  }
}

DEVI s16x8 ldfrag(const ushort* tile, int row, int kc) {
  return *(const s16x8*)((const char*)tile + row * 128 + ((kc ^ (row & 7)) << 4));
}

// =====================================================================
// Single-barrier triple-B K-loop (validated round 9: 232 -> 220 us total).
// BM=BN=128, BK=64, 256 thr / 4 waves (2x2), wave tile 64x64, LDS 80 KiB.
// One s_barrier + one lgkm drain + one counted vmcnt(4) per K-tile.
// =====================================================================
DEVI void kloop3(const ushort* __restrict__ A, const ushort* __restrict__ BT,
                 ushort* Asm, ushort* Bsm, int m0, int n0, int K, int NKT,
                 f32x4 (&acc)[4][4], int tid, int wm, int wn, int g, int l15) {
  stage128q(A + (size_t)m0 * K, K, Asm, tid);
  stage128q(BT + (size_t)n0 * K, K, Bsm, tid);
  stage128q(BT + (size_t)n0 * K + 64, K, Bsm + 8192, tid);
  asm volatile("s_waitcnt vmcnt(4)");
  SBAR();

  int rd = 0;                       // B read-buffer index = t % 3
  #pragma unroll 1
  for (int t = 0; t < NKT; ++t) {
    const ushort* Ah = Asm + (t & 1) * 8192;
    const ushort* Bh = Bsm + rd * 8192;
    s16x8 af[4][2], bfr[4][2];

    #pragma unroll
    for (int ks = 0; ks < 2; ++ks) {
      #pragma unroll
      for (int ni = 0; ni < 4; ++ni)
        bfr[ni][ks] = ldfrag(Bh, wn * 64 + ni * 16 + l15, ks * 4 + g);
      #pragma unroll
      for (int mi = 0; mi < 4; ++mi)
        af[mi][ks] = ldfrag(Ah, wm * 64 + mi * 16 + l15, ks * 4 + g);
    }
    if (t + 1 < NKT)
      stage128q(A + (size_t)m0 * K + (t + 1) * 64, K, Asm + ((t + 1) & 1) * 8192, tid);
    int wr = rd + 2; if (wr >= 3) wr -= 3;           // (t+2) % 3
    if (t + 2 < NKT)
      stage128q(BT + (size_t)n0 * K + (t + 2) * 64, K, Bsm + wr * 8192, tid);

    LGKM0();
    __builtin_amdgcn_sched_barrier(0);
    __builtin_amdgcn_s_setprio(1);
    #pragma unroll
    for (int mi = 0; mi < 4; ++mi)
      #pragma unroll
      for (int ni = 0; ni < 2; ++ni)
        #pragma unroll
        for (int ks = 0; ks < 2; ++ks)
          acc[mi][ni] = MFMA16(af[mi][ks], bfr[ni][ks], acc[mi][ni], 0, 0, 0);
    #pragma unroll
    for (int mi = 0; mi < 4; ++mi)
      #pragma unroll
      for (int ni = 0; ni < 2; ++ni)
        #pragma unroll
        for (int ks = 0; ks < 2; ++ks)
          acc[mi][2 + ni] = MFMA16(af[mi][ks], bfr[2 + ni][ks], acc[mi][2 + ni], 0, 0, 0);
    __builtin_amdgcn_s_setprio(0);

    if (t + 2 < NKT)      asm volatile("s_waitcnt vmcnt(4)");
    else if (t + 1 < NKT) asm volatile("s_waitcnt vmcnt(0)");
    SBAR();
    rd = (rd == 2) ? 0 : rd + 1;
  }
}

// ---------------- elementwise cast ----------------
__global__ __launch_bounds__(256) void cast_bf16_k(const float* __restrict__ in,
                                                   ushort* __restrict__ out, int n) {
  int i = (blockIdx.x * 256 + threadIdx.x) * 4;
  if (i >= n) return;
  float4 v = *(const float4*)(in + i);
  ushort4 o;
  o.x = f2bf(v.x); o.y = f2bf(v.y); o.z = f2bf(v.z); o.w = f2bf(v.w);
  *(ushort4*)(out + i) = o;
}

// ---------------- transpose + cast: in (R,C) f32 -> out (C,R) bf16 ----------------
__global__ __launch_bounds__(256) void transpose_cast_k(const float* __restrict__ in,
                                                        ushort* __restrict__ out, int R, int C) {
  __shared__ ushort tile[64][66];
  const int r0 = blockIdx.y * 64, c0 = blockIdx.x * 64;
  const int tid = threadIdx.x;
  #pragma unroll
  for (int j = 0; j < 16; ++j) {
    int idx = j * 256 + tid;
    int r = idx >> 6, c = idx & 63;
    tile[c][r] = f2bf(in[(size_t)(r0 + r) * C + c0 + c]);
  }
  __syncthreads();
  #pragma unroll
  for (int j = 0; j < 16; ++j) {
    int idx = j * 256 + tid;
    int c = idx >> 6, r = idx & 63;
    out[(size_t)(c0 + c) * R + r0 + r] = tile[c][r];
  }
}

// ---------------- RoPE tables ----------------
__global__ __launch_bounds__(256) void rope_table_k(float2* __restrict__ tab) {
  int idx = blockIdx.x * 256 + threadIdx.x;   // T*32 = 65536
  int t = idx >> 5, i = idx & 31;
  float inv = expf(-(float)i * 0.28782313662425575f);  // ln(10000)/32
  float ang = (float)t * inv;
  tab[idx] = make_float2(cosf(ang), sinf(ang));
}

// ---------------- fused QKV GEMM: 128x128 tile, single-barrier engine ----------------
__global__ __launch_bounds__(256) void gemm_qkv_3b(const ushort* __restrict__ A,
                                                   const ushort* __restrict__ BT,
                                                   const float2* __restrict__ tab,
                                                   ushort* __restrict__ Qp,
                                                   ushort* __restrict__ Kp,
                                                   ushort* __restrict__ Vp) {
  constexpr int K = 2048, NKT = 32;
  __shared__ __attribute__((aligned(128))) ushort smem[40960];   // 80 KiB
  ushort* Asm = smem;            // [2][128*64]
  ushort* Bsm = smem + 16384;    // [3][128*64]
  ushort* Ot = smem;             // epilogue tile [128][132] (33.8 KB, reuse)

  const int tid = threadIdx.x;
  const int ln = tid & 63, wv = tid >> 6;
  const int g = ln >> 4, l15 = ln & 15, l31 = ln & 31, hi = ln >> 5;
  const int wm = wv >> 1, wn = wv & 1;
  const int m0 = blockIdx.y * 128, n0 = blockIdx.x * 128;

  f32x4 acc[4][4];
  #pragma unroll
  for (int i = 0; i < 4; ++i)
    #pragma unroll
    for (int j = 0; j < 4; ++j) acc[i][j] = (f32x4){0.f, 0.f, 0.f, 0.f};

  kloop3(A, BT, Asm, Bsm, m0, n0, K, NKT, acc, tid, wm, wn, g, l15);

  // ---- epilogue: RoPE in-register, bf16 tile to LDS, packed chunk stores ----
  __syncthreads();                 // all waves done reading Asm/Bsm
  const int bq = m0 >> 11;         // batch (block-uniform)
  const int tg0 = m0 & 2047;       // first global t of this block
  const int type = (n0 < 2048) ? 0 : (n0 < 2560 ? 1 : 2);   // Q / K / V

  #pragma unroll
  for (int mi = 0; mi < 4; ++mi)
    #pragma unroll
    for (int r = 0; r < 4; ++r) {
      const int tl = wm * 64 + mi * 16 + g * 4 + r;       // local t row
      const int t = tg0 + tl;
      #pragma unroll
      for (int ni = 0; ni < 4; ++ni) {
        const int cl = wn * 64 + ni * 16 + l15;           // local col
        float val = acc[mi][ni][r];
        float outv;
        if (type < 2) {                                    // RoPE (Q and K)
          float pairv = acc[mi][ni ^ 2][r];
          float2 cs = tab[t * 32 + (ni & 1) * 16 + l15];
          outv = (ni & 2) ? (val * cs.x + pairv * cs.y) : (val * cs.x - pairv * cs.y);
          if (type == 0) outv *= 0.18033688011112042f;     // 0.125 * log2(e)
        } else {
          outv = val;
        }
        Ot[tl * 132 + cl] = f2bf(outv);
      }
    }
  __syncthreads();

  // 32 chunks: id = wv*8+it -> hl = id>>4 (head-local), q4 = (id>>2)&3, fi = id&3
  #pragma unroll
  for (int it = 0; it < 8; ++it) {
    const int id = wv * 8 + it;
    const int hl = id >> 4, q4 = (id >> 2) & 3, fi = id & 3;
    const int tile = (tg0 >> 5) + q4;
    if (type < 2) {
      const ushort* srow = Ot + (q4 * 32 + l31) * 132 + hl * 64 + fi * 16 + hi * 8;
      union { s16x4 h[2]; s16x8 v; } u;
      u.h[0] = *(const s16x4*)srow;
      u.h[1] = *(const s16x4*)(srow + 4);
      ushort* dst;
      if (type == 0) {
        const int h = (n0 >> 6) + hl;
        dst = Qp + (((size_t)(bq * 32 + h) * 64 + tile) * 4 + fi) * 512 + ln * 8;
      } else {
        const int h = ((n0 - 2048) >> 6) + hl;
        dst = Kp + (((size_t)(bq * 8 + h) * 64 + tile) * 4 + fi) * 512 + ln * 8;
      }
      *(s16x8*)dst = u.v;
    } else {
      const int hk = ((n0 - 2560) >> 6) + hl;
      const int col = hl * 64 + (fi & 1) * 32 + l31;
      const int row0 = q4 * 32 + (fi >> 1) * 16 + hi * 8;
      ushort o[8];
      #pragma unroll
      for (int j = 0; j < 8; ++j) o[j] = Ot[(row0 + j) * 132 + col];
      ushort* dst = Vp + (((size_t)(bq * 8 + hk) * 64 + tile) * 4 + fi) * 512 + ln * 8;
      *(s16x8*)dst = *(const s16x8*)o;
    }
  }
}

// ---------------- Wo GEMM: 128x128 tile, single-barrier engine, f32 store ----------------
__global__ __launch_bounds__(256) void gemm_bt_3b(const ushort* __restrict__ A,
                                                  const ushort* __restrict__ BT,
                                                  float* __restrict__ C, int M, int N, int K) {
  __shared__ __attribute__((aligned(128))) ushort smem[40960];   // 80 KiB
  ushort* Asm = smem;
  ushort* Bsm = smem + 16384;

  const int tid = threadIdx.x;
  const int ln = tid & 63, wv = tid >> 6;
  const int g = ln >> 4, l15 = ln & 15;
  const int wm = wv >> 1, wn = wv & 1;
  const int m0 = blockIdx.y * 128, n0 = blockIdx.x * 128;
  const int NKT = K / 64;

  f32x4 acc[4][4];
  #pragma unroll
  for (int i = 0; i < 4; ++i)
    #pragma unroll
    for (int j = 0; j < 4; ++j) acc[i][j] = (f32x4){0.f, 0.f, 0.f, 0.f};

  kloop3(A, BT, Asm, Bsm, m0, n0, K, NKT, acc, tid, wm, wn, g, l15);

  #pragma unroll
  for (int mi = 0; mi < 4; ++mi)
    #pragma unroll
    for (int r = 0; r < 4; ++r) {
      int row = m0 + wm * 64 + mi * 16 + g * 4 + r;
      float* crow = C + (size_t)row * N + n0 + wn * 64 + l15;
      #pragma unroll
      for (int ni = 0; ni < 4; ++ni) crow[ni * 16] = acc[mi][ni][r];
    }
}

// ---------------- causal GQA flash attention, swapped-QK^T 32x32, barrier-free ----------------
// VALU-diet (round 11 = round 10 fixed): T13 defer-max THR=8; T12 pack via
// __builtin_amdgcn_permlane32_swap (NOT inline asm — see plswap_* comment);
// persistent-zero MFMA C-in.  Round-9 counters: VALUBusy 76.7%, MfmaUtil
// 15.9%, 770K LDS bank conflicts (the shfl_xor ds_bpermutes).
__global__ __launch_bounds__(256) void attn_k(const ushort* __restrict__ Qp,
                                              const ushort* __restrict__ Kp,
                                              const ushort* __restrict__ Vp,
                                              ushort* __restrict__ O) {
  __shared__ ushort ep[4][32 * 64];   // per-wave epilogue transpose patch
  const int tid = threadIdx.x, wv = tid >> 6, ln = tid & 63;
  const int l31 = ln & 31, hi = ln >> 5;

  const int f = blockIdx.x + gridDim.x * (blockIdx.y + 32 * blockIdx.z);  // 0..1023
  const int xcd = f & 7, j = f >> 3;         // j: 0..127
  const int pr = xcd + 8 * (j & 1);          // (b,hk) pair id, 0..15
  const int b = pr >> 3, hk = pr & 7;
  const int s = j >> 1;                      // 0..63
  const int hq = hk * 4 + (s & 3);
  const int qtile = 63 - ((s >> 2) * 4 + wv);   // LJF
  const int qw = qtile * 32;
  const int nt = qtile + 1;

  const ushort* Qh    = Qp + ((size_t)(b * 32 + hq)) * (64 * 2048);
  const ushort* Kbase = Kp + ((size_t)(b * 8 + hk)) * (64 * 2048);
  const ushort* Vbase = Vp + ((size_t)(b * 8 + hk)) * (64 * 2048);
  ushort* lds = ep[wv];

  s16x8 qf[4];
  {
    const ushort* qp_ = Qh + (size_t)qtile * 2048 + ln * 8;
    #pragma unroll
    for (int ks = 0; ks < 4; ++ks) qf[ks] = *(const s16x8*)(qp_ + ks * 512);
  }

  f32x16 z16;
  #pragma unroll
  for (int r = 0; r < 16; ++r) z16[r] = 0.f;

  f32x16 oacc[2];
  #pragma unroll
  for (int dt = 0; dt < 2; ++dt)
    #pragma unroll
    for (int r = 0; r < 16; ++r) oacc[dt][r] = 0.f;
  float m = -1e30f, l = 0.f;

  const ushort* kp = Kbase + ln * 8;
  const ushort* vp = Vbase + ln * 8;

  s16x8 kf[4];
  #pragma unroll
  for (int ks = 0; ks < 4; ++ks) kf[ks] = *(const s16x8*)(kp + ks * 512);
  kp += 2048;

  s16x8 vc[4];
  union pfu { unsigned u[4]; s16x8 v; };
  pfu pf0, pf1;

  #pragma unroll 1
  for (int kt = 0; kt < nt; ++kt) {
    if (kt) {
      __builtin_amdgcn_s_setprio(1);
      oacc[0] = __builtin_amdgcn_mfma_f32_32x32x16_bf16(vc[0], pf0.v, oacc[0], 0, 0, 0);
      oacc[1] = __builtin_amdgcn_mfma_f32_32x32x16_bf16(vc[1], pf0.v, oacc[1], 0, 0, 0);
      oacc[0] = __builtin_amdgcn_mfma_f32_32x32x16_bf16(vc[2], pf1.v, oacc[0], 0, 0, 0);
      oacc[1] = __builtin_amdgcn_mfma_f32_32x32x16_bf16(vc[3], pf1.v, oacc[1], 0, 0, 0);
      __builtin_amdgcn_s_setprio(0);
    }
    #pragma unroll
    for (int fi2 = 0; fi2 < 4; ++fi2) vc[fi2] = *(const s16x8*)(vp + fi2 * 512);
    vp += 2048;

    __builtin_amdgcn_s_setprio(1);
    f32x16 sp = __builtin_amdgcn_mfma_f32_32x32x16_bf16(kf[0], qf[0], z16, 0, 0, 0);
    sp = __builtin_amdgcn_mfma_f32_32x32x16_bf16(kf[1], qf[1], sp, 0, 0, 0);
    sp = __builtin_amdgcn_mfma_f32_32x32x16_bf16(kf[2], qf[2], sp, 0, 0, 0);
    sp = __builtin_amdgcn_mfma_f32_32x32x16_bf16(kf[3], qf[3], sp, 0, 0, 0);
    __builtin_amdgcn_s_setprio(0);

    if (kt + 1 < nt) {
      #pragma unroll
      for (int ks = 0; ks < 4; ++ks) kf[ks] = *(const s16x8*)(kp + ks * 512);
      kp += 2048;
    }

    if (kt == qtile) {
      #pragma unroll
      for (int r = 0; r < 16; ++r) {
        int key = (r & 3) + 8 * (r >> 2) + 4 * hi;
        if (key > l31) sp[r] = -1e30f;
      }
    }

    float t0 = fmaxf(fmaxf(sp[0], sp[1]), sp[2]);
    float t1 = fmaxf(fmaxf(sp[3], sp[4]), sp[5]);
    float t2 = fmaxf(fmaxf(sp[6], sp[7]), sp[8]);
    float t3 = fmaxf(fmaxf(sp[9], sp[10]), sp[11]);
    float t4 = fmaxf(fmaxf(sp[12], sp[13]), sp[14]);
    float u0 = fmaxf(fmaxf(t0, t1), t2);
    float u1 = fmaxf(fmaxf(t3, t4), sp[15]);
    float pm = plswap_max(fmaxf(u0, u1));   // cross-half row max, VALU pipe

    // T13 defer-max: rescale only when some q-row grew by > 8 (exp2 domain);
    // P then bounded by 2^8 = 256 — safe in f32 accum / bf16 pack.
    if (__any(pm - m > 8.0f)) {
      float mn = fmaxf(m, pm);
      float alpha = __builtin_amdgcn_exp2f(m - mn);
      m = mn;
      l *= alpha;
      #pragma unroll
      for (int dt = 0; dt < 2; ++dt)
        #pragma unroll
        for (int r = 0; r < 16; ++r) oacc[dt][r] *= alpha;
    }

    #pragma unroll
    for (int r = 0; r < 16; ++r) sp[r] = __builtin_amdgcn_exp2f(sp[r] - m);
    {
      float a0 = sp[0] + sp[1], a1 = sp[2] + sp[3], a2 = sp[4] + sp[5], a3 = sp[6] + sp[7];
      float a4 = sp[8] + sp[9], a5 = sp[10] + sp[11], a6 = sp[12] + sp[13], a7 = sp[14] + sp[15];
      float b0 = a0 + a1, b1 = a2 + a3, b2 = a4 + a5, b3 = a6 + a7;
      l += plswap_sum((b0 + b1) + (b2 + b3));
    }

    unsigned cw[8];
    #pragma unroll
    for (int jj = 0; jj < 8; ++jj) {
      union { __hip_bfloat162 h; unsigned u; } pk;
      pk.h = __float22bfloat162_rn(make_float2(sp[2 * jj], sp[2 * jj + 1]));
      cw[jj] = pk.u;
    }
    // P-pack: (pf.u[j], pf.u[j+2]) = permlane32_swap(cw[j], cw[j+2]).
    // Verified against the round-9 shfl_xor select table:
    //   lo lane: u[j]=own cw[j],        u[j+2]=partner-hi cw[j]
    //   hi lane: u[j]=partner-lo cw[j+2], u[j+2]=own cw[j+2]
    {
      u32x2 r;
      r = __builtin_amdgcn_permlane32_swap(cw[0], cw[2], false, false);
      pf0.u[0] = r[0]; pf0.u[2] = r[1];
      r = __builtin_amdgcn_permlane32_swap(cw[1], cw[3], false, false);
      pf0.u[1] = r[0]; pf0.u[3] = r[1];
      r = __builtin_amdgcn_permlane32_swap(cw[4], cw[6], false, false);
      pf1.u[0] = r[0]; pf1.u[2] = r[1];
      r = __builtin_amdgcn_permlane32_swap(cw[5], cw[7], false, false);
      pf1.u[1] = r[0]; pf1.u[3] = r[1];
    }
  }

  __builtin_amdgcn_s_setprio(1);
  oacc[0] = __builtin_amdgcn_mfma_f32_32x32x16_bf16(vc[0], pf0.v, oacc[0], 0, 0, 0);
  oacc[1] = __builtin_amdgcn_mfma_f32_32x32x16_bf16(vc[1], pf0.v, oacc[1], 0, 0, 0);
  oacc[0] = __builtin_amdgcn_mfma_f32_32x32x16_bf16(vc[2], pf1.v, oacc[0], 0, 0, 0);
  oacc[1] = __builtin_amdgcn_mfma_f32_32x32x16_bf16(vc[3], pf1.v, oacc[1], 0, 0, 0);
  __builtin_amdgcn_s_setprio(0);

  float invl = 1.0f / l;
  #pragma unroll
  for (int dt = 0; dt < 2; ++dt)
    #pragma unroll
    for (int r = 0; r < 16; ++r) {
      int d = dt * 32 + (r & 3) + 8 * (r >> 2) + 4 * hi;
      int byte = (l31 * 128 + d * 2) ^ ((l31 & 7) << 4);
      *(ushort*)((char*)lds + byte) = f2bf(oacc[dt][r] * invl);
    }
  const int qr = ln >> 1, half = ln & 1;
  #pragma unroll
  for (int jj = 0; jj < 4; ++jj) {
    int byte = (qr * 128 + half * 64 + jj * 16) ^ ((qr & 7) << 4);
    s16x8 vrow = *(const s16x8*)((const char*)lds + byte);
    *(s16x8*)(O + ((size_t)(b * 2048 + qw + qr)) * 2048 + hq * 64 + half * 32 + jj * 8) = vrow;
  }
}

extern "C" void kernel_launch(void* const* d_in, const int* in_sizes, int n_in,
                              void* d_out, int out_size, void* d_ws, size_t ws_size,
                              hipStream_t stream) {
  const float* x   = (const float*)d_in[0];
  const float* Wq  = (const float*)d_in[1];
  const float* Wkv = (const float*)d_in[2];
  const float* Wo  = (const float*)d_in[3];
  float* out = (float*)d_out;

  char* ws = (char*)d_ws;
  ushort* xb     = (ushort*)(ws);                 // 16 MiB  x bf16 (4096x2048)
  ushort* WqkvT  = (ushort*)(ws + 16777216);      // 12 MiB  [Wq|Wkv]^T bf16 (3072x2048)
  ushort* WoT    = (ushort*)(ws + 29360128);      //  8 MiB  Wo^T bf16 (2048x2048)
  float2* tab    = (float2*)(ws + 37748736);      // 512 KiB rope tables
  ushort* Qp     = (ushort*)(ws + 38273024);      // 16 MiB  Q packed
  ushort* Kp     = (ushort*)(ws + 55050240);      //  4 MiB  K packed
  ushort* Vp     = (ushort*)(ws + 59244544);      //  4 MiB  V packed
  ushort* Ob     = (ushort*)(ws + 63438848);      // 16 MiB  attn out bf16 (4096x2048)

  cast_bf16_k<<<8192, 256, 0, stream>>>(x, xb, 2 * 2048 * 2048);
  transpose_cast_k<<<dim3(32, 32), 256, 0, stream>>>(Wq, WqkvT, 2048, 2048);
  transpose_cast_k<<<dim3(16, 32), 256, 0, stream>>>(Wkv, WqkvT + 2048 * 2048, 2048, 1024);
  transpose_cast_k<<<dim3(32, 32), 256, 0, stream>>>(Wo, WoT, 2048, 2048);
  rope_table_k<<<256, 256, 0, stream>>>(tab);
  gemm_qkv_3b<<<dim3(24, 32), 256, 0, stream>>>(xb, WqkvT, tab, Qp, Kp, Vp);
  attn_k<<<dim3(16, 32, 2), 256, 0, stream>>>(Qp, Kp, Vp, Ob);
  gemm_bt_3b<<<dim3(16, 32), 256, 0, stream>>>(Ob, WoT, out, 4096, 2048, 2048);
}